// Round 6
// baseline (3651.291 us; speedup 1.0000x reference)
//
#include <hip/hip_runtime.h>
#include <hip/hip_bf16.h>

typedef __hip_bfloat16 bf16;

#define B_     16
#define N_     48
#define NODES  768
#define PAIRS  2256   // ordered pairs (i!=j) per batch
#define EB     4512   // edges per batch (2 classes)
#define EK     36096  // kept edges total
#define S_     2256   // kept edges per batch
#define SH     1128   // S/2
#define D_     192

__device__ __forceinline__ float bf(const bf16* p, int i) { return __bfloat162float(p[i]); }
__device__ __forceinline__ float sanitize(float v) {
    if (v > -1e4f && v < 1e4f) return v;
    if (v >= 1e4f) return 1e4f;
    if (v <= -1e4f) return -1e4f;
    return 0.f;  // NaN
}

// ---------------- K1: edge weight embedding, summed over the 2 classes ----------------
__global__ __launch_bounds__(256) void edgew_kernel(const bf16* edge_attr, const bf16* W_we,
                                                    const bf16* b_we, float* ws_sum) {
    int idx = blockIdx.x * 256 + threadIdx.x;
    if (idx >= B_ * N_ * N_) return;
    int b = idx / (N_ * N_), r = idx % (N_ * N_), i = r / N_, j = r % N_;
    if (i == j) { ws_sum[idx] = 0.f; return; }
    int p = i * 47 + (j < i ? j : j - 1);
    int e = (b * PAIRS + p) * 2;  // class-0 edge; class-1 is e+1
    float we0 = bf(W_we, 0), we1 = bf(W_we, 1), we2 = bf(W_we, 2), bw = bf(b_we, 0);
    float w0 = fmaxf(we0 * bf(edge_attr, (e + 0) * 2) + we1 + bw, 0.f);
    float w1 = fmaxf(we0 * bf(edge_attr, (e + 1) * 2) + we2 + bw, 0.f);
    ws_sum[idx] = w0 + w1;
}

// ---------------- K2: fused 2-layer GraphConv, one block per batch ----------------
__global__ __launch_bounds__(256) void graphconv_kernel(
    const float* ws_sum, const bf16* x,
    const bf16* Wrel1, const bf16* brel1, const bf16* Wroot1,
    const bf16* Wrel2, const bf16* brel2, const bf16* Wroot2, float* x2out) {
    int b = blockIdx.x, tid = threadIdx.x;
    __shared__ float s_ws[N_ * N_];   // [src][dst]
    __shared__ float s_x[N_ * 5], s_agg1[N_ * 5];
    __shared__ float s_x1[N_ * 32], s_agg2[N_ * 32];
    for (int idx = tid; idx < N_ * N_; idx += 256) s_ws[idx] = ws_sum[b * N_ * N_ + idx];
    for (int idx = tid; idx < N_ * 5; idx += 256) s_x[idx] = bf(x, b * N_ * 5 + idx);
    __syncthreads();
    if (tid < 240) {  // agg1[j][f] = sum_i ws[i][j] * x[i][f]
        int j = tid / 5, f = tid % 5;
        float a = 0.f;
        for (int i = 0; i < N_; i++) a += s_ws[i * N_ + j] * s_x[i * 5 + f];
        s_agg1[tid] = a;
    }
    __syncthreads();
    for (int o = tid; o < N_ * 32; o += 256) {
        int j = o >> 5, h = o & 31;
        float a = bf(brel1, h);
        for (int f = 0; f < 5; f++)
            a += bf(Wrel1, h * 5 + f) * s_agg1[j * 5 + f] + bf(Wroot1, h * 5 + f) * s_x[j * 5 + f];
        s_x1[o] = fmaxf(a, 0.f);
    }
    __syncthreads();
    for (int o = tid; o < N_ * 32; o += 256) {
        int j = o >> 5, h = o & 31;
        float a = 0.f;
        for (int i = 0; i < N_; i++) a += s_ws[i * N_ + j] * s_x1[i * 32 + h];
        s_agg2[o] = a;
    }
    __syncthreads();
    for (int o = tid; o < N_ * 64; o += 256) {
        int j = o >> 6, h2 = o & 63;
        float a = bf(brel2, h2);
        for (int h1 = 0; h1 < 32; h1++)
            a += bf(Wrel2, h2 * 32 + h1) * s_agg2[j * 32 + h1] +
                 bf(Wroot2, h2 * 32 + h1) * s_x1[j * 32 + h1];
        x2out[(b * N_ + j) * 64 + h2] = fmaxf(a, 0.f);
    }
}

// ---------------- K3: weight composition, stage A (vectors) ----------------
__global__ __launch_bounds__(256) void compose_a(
    const bf16* W_o, const bf16* b_o, const bf16* W_out, const bf16* b_out,
    const bf16* W_in, const bf16* b_in, const bf16* b_qkv,
    float* wo_eff, float* bq_eff, float* bk_eff, float* t_m, float* sc) {
    __shared__ float s_wo[D_], s_bv[D_];
    int tid = threadIdx.x;
    if (tid < D_) {
        float a = 0.f;
        for (int d = 0; d < D_; d++) a += bf(W_o, d) * bf(W_out, d * D_ + tid);
        s_wo[tid] = a; wo_eff[tid] = a;
        float aq = bf(b_in, tid), ak = bf(b_in, D_ + tid), av = bf(b_in, 2 * D_ + tid);
        for (int m = 0; m < D_; m++) {
            aq += bf(W_in, tid * D_ + m) * bf(b_qkv, m);
            ak += bf(W_in, (D_ + tid) * D_ + m) * bf(b_qkv, D_ + m);
            av += bf(W_in, (2 * D_ + tid) * D_ + m) * bf(b_qkv, 2 * D_ + m);
        }
        bq_eff[tid] = aq; bk_eff[tid] = ak; s_bv[tid] = av;
    }
    __syncthreads();
    if (tid < D_) {
        float a = 0.f;
        for (int aa = 0; aa < D_; aa++) a += s_wo[aa] * bf(W_in, (2 * D_ + aa) * D_ + tid);
        t_m[tid] = a;
    }
    if (tid == 0) {
        float bvl = 0.f, co = bf(b_o, 0);
        for (int aa = 0; aa < D_; aa++) bvl += s_wo[aa] * s_bv[aa];
        for (int d = 0; d < D_; d++) co += bf(W_o, d) * bf(b_out, d);
        sc[0] = bvl;  // vl bias
        sc[1] = co;   // final logit constant
    }
}

// ---------------- K4: weight composition, stage B (matrices) ----------------
__global__ __launch_bounds__(256) void compose_b(const bf16* W_in, const bf16* W_qkv,
                                                 const float* t_m, float* Wq_eff,
                                                 float* Wk_eff, float* wvl) {
    int idx = blockIdx.x * 256 + threadIdx.x;
    if (idx < D_ * D_) {
        int a = idx / D_, c = idx % D_;
        float acc = 0.f;
        for (int m = 0; m < D_; m++) acc += bf(W_in, a * D_ + m) * bf(W_qkv, m * D_ + c);
        Wq_eff[idx] = acc;
    } else if (idx < 2 * D_ * D_) {
        int t = idx - D_ * D_, a = t / D_, c = t % D_;
        float acc = 0.f;
        for (int m = 0; m < D_; m++)
            acc += bf(W_in, (D_ + a) * D_ + m) * bf(W_qkv, (D_ + m) * D_ + c);
        Wk_eff[t] = acc;
    } else if (idx < 2 * D_ * D_ + D_) {
        int c = idx - 2 * D_ * D_;
        float acc = 0.f;
        for (int m = 0; m < D_; m++) acc += t_m[m] * bf(W_qkv, (2 * D_ + m) * D_ + c);
        wvl[c] = acc;
    }
}

// ---------------- K5: fused feat-build + Q/K/vl projections (32 tokens/block) ----------
__global__ __launch_bounds__(256) void qkv_kernel(const float* x2, const bf16* edge_attr,
                                                  const bf16* W_ee, const bf16* b_ee,
                                                  const float* Wq_eff, const float* Wk_eff,
                                                  const float* wvl, const float* bq_eff,
                                                  const float* bk_eff, const float* sc,
                                                  float* Q, float* K, float* vl) {
    __shared__ float s_feat[32 * 193];
    __shared__ int s_i[32], s_j[32], s_b[32], s_cls[32];
    __shared__ float s_w[32];
    int tid = threadIdx.x, base = blockIdx.x * 32;
    if (tid < 32) {
        int kk_g = base + tid;
        int b = kk_g / S_, kk = kk_g % S_;
        int q = kk >> 1, cls = kk & 1;
        int i = (int)((1.0f + sqrtf(8.0f * (float)q + 1.0f)) * 0.5f);
        while (i * (i - 1) / 2 > q) --i;
        while ((i + 1) * i / 2 <= q) ++i;
        int j = q - i * (i - 1) / 2;  // j < i
        s_i[tid] = i; s_j[tid] = j; s_b[tid] = b; s_cls[tid] = cls;
        int e = (b * PAIRS + i * 47 + j) * 2 + cls;
        s_w[tid] = bf(edge_attr, e * 2);
    }
    __syncthreads();
    for (int idx = tid; idx < 32 * 64; idx += 256) {
        int t = idx >> 6, h = idx & 63;
        int bb = s_b[t], cls = s_cls[t];
        float w = bf(W_ee, h * 3) * s_w[t] + bf(W_ee, h * 3 + 1 + cls) + bf(b_ee, h);
        float* fr = &s_feat[t * 193];
        fr[h]       = x2[(bb * N_ + s_i[t]) * 64 + h];
        fr[64 + h]  = fmaxf(w, 0.f);
        fr[128 + h] = x2[(bb * N_ + s_j[t]) * 64 + h];
    }
    __syncthreads();
    int tok = tid >> 3, g = tid & 7;
    const float* fr = &s_feat[tok * 193];
    for (int am = 0; am < 24; ++am) {
        int a = g * 24 + am;
        float accq = bq_eff[a], acck = bk_eff[a];
        const float* wq = &Wq_eff[a * D_];
        const float* wk = &Wk_eff[a * D_];
        for (int c = 0; c < D_; c++) { float f = fr[c]; accq += wq[c] * f; acck += wk[c] * f; }
        Q[(long)(base + tok) * D_ + a] = accq;
        K[(long)(base + tok) * D_ + a] = acck;
    }
    if (tid < 32) {
        float a = sc[0];
        for (int c = 0; c < D_; c++) a += wvl[c] * s_feat[tid * 193 + c];
        vl[base + tid] = a;
    }
}

// ---------------- K6: scalar-value flash attention -> logit ----------------
__global__ __launch_bounds__(256) void attn_kernel(const float* Q, const float* K,
                                                   const float* vl, const float* sc,
                                                   float* logit) {
    int blk = blockIdx.x;
    int b = blk / 141, qt = blk % 141;
    int qbase = b * S_ + qt * 16;
    __shared__ float s_q[16 * 193], s_k[16 * 193], s_vl[16];
    int tid = threadIdx.x;
    for (int idx = tid; idx < 16 * D_; idx += 256) {
        int r = idx / D_, c = idx % D_;
        s_q[r * 193 + c] = Q[(long)(qbase + r) * D_ + c];
    }
    int qi = tid >> 4, ki = tid & 15;
    float m = -1e30f, l = 0.f, acc = 0.f;
    const float scale = 0.0721687836487032f;  // 1/sqrt(192)
    for (int kt = 0; kt < 141; ++kt) {
        __syncthreads();
        int kbase = b * S_ + kt * 16;
        for (int idx = tid; idx < 16 * D_; idx += 256) {
            int r = idx / D_, c = idx % D_;
            s_k[r * 193 + c] = K[(long)(kbase + r) * D_ + c];
        }
        if (tid < 16) s_vl[tid] = vl[kbase + tid];
        __syncthreads();
        const float* qr = &s_q[qi * 193];
        const float* kr = &s_k[ki * 193];
        float d = 0.f;
        for (int c = 0; c < D_; c++) d += qr[c] * kr[c];
        float s = d * scale;
        float tmax = s;
        for (int off = 8; off; off >>= 1) tmax = fmaxf(tmax, __shfl_xor(tmax, off, 64));
        float newm = fmaxf(m, tmax);
        float p = __expf(s - newm);
        float pv = p * s_vl[ki];
        float sp = p, spv = pv;
        for (int off = 8; off; off >>= 1) {
            sp += __shfl_xor(sp, off, 64);
            spv += __shfl_xor(spv, off, 64);
        }
        float alpha = __expf(m - newm);
        l = l * alpha + sp;
        acc = acc * alpha + spv;
        m = newm;
    }
    if (ki == 0) logit[qbase + qi] = sanitize(acc / l + sc[1]);
}

// ---------------- K7: pairing / argmin epilogue — d_out is FLOAT32 ----------------
__global__ __launch_bounds__(256) void final_kernel(const float* logit, float* out) {
    int idx = blockIdx.x * 256 + threadIdx.x;
    if (idx >= B_ * SH) return;
    int b = idx / SH, p = idx % SH;
    int i = (int)((1.0f + sqrtf(8.0f * (float)p + 1.0f)) * 0.5f);
    while (i * (i - 1) / 2 > p) --i;
    while ((i + 1) * i / 2 <= p) ++i;
    int j = p - i * (i - 1) / 2;
    float l0 = sanitize(logit[b * S_ + 2 * p]), l1 = sanitize(logit[b * S_ + 2 * p + 1]);
    int ind = (l1 < l0) ? 1 : 0;                 // np.argmin: first wins on tie
    float ef = ind ? l1 : l0;
    out[(b * SH + p) * 2 + 0] = (float)(b * N_ + i);  // src
    out[(b * SH + p) * 2 + 1] = (float)(b * N_ + j);  // dst
    out[2 * B_ * SH + idx] = ef;
    out[2 * B_ * SH + B_ * SH + idx] = (float)ind;
}

extern "C" void kernel_launch(void* const* d_in, const int* in_sizes, int n_in,
                              void* d_out, int out_size, void* d_ws, size_t ws_size,
                              hipStream_t stream) {
    const bf16* x         = (const bf16*)d_in[0];
    const bf16* edge_attr = (const bf16*)d_in[2];
    const bf16* W_we   = (const bf16*)d_in[5];
    const bf16* b_we   = (const bf16*)d_in[6];
    const bf16* Wrel1  = (const bf16*)d_in[7];
    const bf16* brel1  = (const bf16*)d_in[8];
    const bf16* Wroot1 = (const bf16*)d_in[9];
    const bf16* Wrel2  = (const bf16*)d_in[10];
    const bf16* brel2  = (const bf16*)d_in[11];
    const bf16* Wroot2 = (const bf16*)d_in[12];
    const bf16* W_ee   = (const bf16*)d_in[13];
    const bf16* b_ee   = (const bf16*)d_in[14];
    const bf16* W_qkv  = (const bf16*)d_in[15];
    const bf16* b_qkv  = (const bf16*)d_in[16];
    const bf16* W_in   = (const bf16*)d_in[17];
    const bf16* b_in   = (const bf16*)d_in[18];
    const bf16* W_out  = (const bf16*)d_in[19];
    const bf16* b_out  = (const bf16*)d_in[20];
    const bf16* W_o    = (const bf16*)d_in[21];
    const bf16* b_o    = (const bf16*)d_in[22];

    float* w = (float*)d_ws;
    float* Wq_eff = w;                 // 36864 f
    float* Wk_eff = Wq_eff + 36864;    // 36864 f
    float* wvl    = Wk_eff + 36864;    // 192 f
    float* bq_eff = wvl + 192;
    float* bk_eff = bq_eff + 192;
    float* wo_eff = bk_eff + 192;
    float* t_m    = wo_eff + 192;
    float* sc     = t_m + 192;         // 64 f (2 used)
    float* ws_sum = sc + 64;           // 36864 f
    float* x2     = ws_sum + 36864;    // 49152 f
    float* vl     = x2 + 49152;        // 36096 f
    float* logit  = vl + 36096;        // 36096 f
    float* Q      = logit + 36096;     // 6,930,432 f
    float* K      = Q + (long)EK * D_; // 6,930,432 f
    // total ~56.2 MB of workspace (ws_size = 256 MB)

    edgew_kernel<<<(B_ * N_ * N_ + 255) / 256, 256, 0, stream>>>(edge_attr, W_we, b_we, ws_sum);
    graphconv_kernel<<<B_, 256, 0, stream>>>(ws_sum, x, Wrel1, brel1, Wroot1, Wrel2, brel2,
                                             Wroot2, x2);
    compose_a<<<1, 256, 0, stream>>>(W_o, b_o, W_out, b_out, W_in, b_in, b_qkv, wo_eff, bq_eff,
                                     bk_eff, t_m, sc);
    compose_b<<<(2 * D_ * D_ + D_ + 255) / 256, 256, 0, stream>>>(W_in, W_qkv, t_m, Wq_eff,
                                                                  Wk_eff, wvl);
    qkv_kernel<<<EK / 32, 256, 0, stream>>>(x2, edge_attr, W_ee, b_ee, Wq_eff, Wk_eff, wvl,
                                            bq_eff, bk_eff, sc, Q, K, vl);
    attn_kernel<<<B_ * 141, 256, 0, stream>>>(Q, K, vl, sc, logit);
    final_kernel<<<(B_ * SH + 255) / 256, 256, 0, stream>>>(logit, (float*)d_out);
}

// Round 7
// 386.512 us; speedup vs baseline: 9.4468x; 9.4468x over previous
//
#include <hip/hip_runtime.h>
#include <hip/hip_bf16.h>

typedef __hip_bfloat16 bf16;
typedef __attribute__((ext_vector_type(8))) short short8;
typedef __attribute__((ext_vector_type(8))) unsigned short ushort8;
typedef __attribute__((ext_vector_type(16))) float float16v;
typedef __attribute__((ext_vector_type(4))) float float4v;

#define B_     16
#define N_     48
#define NODES  768
#define PAIRS  2256   // ordered pairs (i!=j) per batch
#define EK     36096  // kept edges total
#define S_     2256   // kept edges per batch
#define SH     1128   // S/2
#define D_     192
#define KITERS 71     // ceil(2256/32)
#define QTILES 71     // ceil(2256/32)
#define QSCALE 0.10411754f  // log2(e)/sqrt(192): folded into Q at store

__device__ __forceinline__ float bf(const bf16* p, int i) { return __bfloat162float(p[i]); }
__device__ __forceinline__ float u2f(unsigned short u) {
    return __uint_as_float(((unsigned int)u) << 16);
}
__device__ __forceinline__ float sanitize(float v) {
    if (v > -1e4f && v < 1e4f) return v;
    if (v >= 1e4f) return 1e4f;
    if (v <= -1e4f) return -1e4f;
    return 0.f;  // NaN
}

// ---------------- K1: edge weight embedding, summed over the 2 classes ----------------
__global__ __launch_bounds__(256) void edgew_kernel(const bf16* edge_attr, const bf16* W_we,
                                                    const bf16* b_we, float* ws_sum) {
    int idx = blockIdx.x * 256 + threadIdx.x;
    if (idx >= B_ * N_ * N_) return;
    int b = idx / (N_ * N_), r = idx % (N_ * N_), i = r / N_, j = r % N_;
    if (i == j) { ws_sum[idx] = 0.f; return; }
    int p = i * 47 + (j < i ? j : j - 1);
    int e = (b * PAIRS + p) * 2;
    float we0 = bf(W_we, 0), we1 = bf(W_we, 1), we2 = bf(W_we, 2), bw = bf(b_we, 0);
    float w0 = fmaxf(we0 * bf(edge_attr, (e + 0) * 2) + we1 + bw, 0.f);
    float w1 = fmaxf(we0 * bf(edge_attr, (e + 1) * 2) + we2 + bw, 0.f);
    ws_sum[idx] = w0 + w1;
}

// ---------------- K2: fused 2-layer GraphConv, one block per batch ----------------
__global__ __launch_bounds__(256) void graphconv_kernel(
    const float* ws_sum, const bf16* x,
    const bf16* Wrel1, const bf16* brel1, const bf16* Wroot1,
    const bf16* Wrel2, const bf16* brel2, const bf16* Wroot2, float* x2out) {
    int b = blockIdx.x, tid = threadIdx.x;
    __shared__ float s_ws[N_ * N_];
    __shared__ float s_x[N_ * 5], s_agg1[N_ * 5];
    __shared__ float s_x1[N_ * 32], s_agg2[N_ * 32];
    for (int idx = tid; idx < N_ * N_; idx += 256) s_ws[idx] = ws_sum[b * N_ * N_ + idx];
    for (int idx = tid; idx < N_ * 5; idx += 256) s_x[idx] = bf(x, b * N_ * 5 + idx);
    __syncthreads();
    if (tid < 240) {
        int j = tid / 5, f = tid % 5;
        float a = 0.f;
        for (int i = 0; i < N_; i++) a += s_ws[i * N_ + j] * s_x[i * 5 + f];
        s_agg1[tid] = a;
    }
    __syncthreads();
    for (int o = tid; o < N_ * 32; o += 256) {
        int j = o >> 5, h = o & 31;
        float a = bf(brel1, h);
        for (int f = 0; f < 5; f++)
            a += bf(Wrel1, h * 5 + f) * s_agg1[j * 5 + f] + bf(Wroot1, h * 5 + f) * s_x[j * 5 + f];
        s_x1[o] = fmaxf(a, 0.f);
    }
    __syncthreads();
    for (int o = tid; o < N_ * 32; o += 256) {
        int j = o >> 5, h = o & 31;
        float a = 0.f;
        for (int i = 0; i < N_; i++) a += s_ws[i * N_ + j] * s_x1[i * 32 + h];
        s_agg2[o] = a;
    }
    __syncthreads();
    for (int o = tid; o < N_ * 64; o += 256) {
        int j = o >> 6, h2 = o & 63;
        float a = bf(brel2, h2);
        for (int h1 = 0; h1 < 32; h1++)
            a += bf(Wrel2, h2 * 32 + h1) * s_agg2[j * 32 + h1] +
                 bf(Wroot2, h2 * 32 + h1) * s_x1[j * 32 + h1];
        x2out[(b * N_ + j) * 64 + h2] = fmaxf(a, 0.f);
    }
}

// ---------------- K3: weight composition, stage A (vectors) ----------------
__global__ __launch_bounds__(256) void compose_a(
    const bf16* W_o, const bf16* b_o, const bf16* W_out, const bf16* b_out,
    const bf16* W_in, const bf16* b_in, const bf16* b_qkv,
    float* wo_eff, float* bq_eff, float* bk_eff, float* t_m, float* sc) {
    __shared__ float s_wo[D_], s_bv[D_];
    int tid = threadIdx.x;
    if (tid < D_) {
        float a = 0.f;
        for (int d = 0; d < D_; d++) a += bf(W_o, d) * bf(W_out, d * D_ + tid);
        s_wo[tid] = a; wo_eff[tid] = a;
        float aq = bf(b_in, tid), ak = bf(b_in, D_ + tid), av = bf(b_in, 2 * D_ + tid);
        for (int m = 0; m < D_; m++) {
            aq += bf(W_in, tid * D_ + m) * bf(b_qkv, m);
            ak += bf(W_in, (D_ + tid) * D_ + m) * bf(b_qkv, D_ + m);
            av += bf(W_in, (2 * D_ + tid) * D_ + m) * bf(b_qkv, 2 * D_ + m);
        }
        bq_eff[tid] = aq; bk_eff[tid] = ak; s_bv[tid] = av;
    }
    __syncthreads();
    if (tid < D_) {
        float a = 0.f;
        for (int aa = 0; aa < D_; aa++) a += s_wo[aa] * bf(W_in, (2 * D_ + aa) * D_ + tid);
        t_m[tid] = a;
    }
    if (tid == 0) {
        float bvl = 0.f, co = bf(b_o, 0);
        for (int aa = 0; aa < D_; aa++) bvl += s_wo[aa] * s_bv[aa];
        for (int d = 0; d < D_; d++) co += bf(W_o, d) * bf(b_out, d);
        sc[0] = bvl;  // vl bias
        sc[1] = co;   // final logit constant
    }
}

// ---------------- K4: weight composition, stage B (matrices) ----------------
__global__ __launch_bounds__(256) void compose_b(const bf16* W_in, const bf16* W_qkv,
                                                 const float* t_m, float* Wq_eff,
                                                 float* Wk_eff, float* wvl) {
    int idx = blockIdx.x * 256 + threadIdx.x;
    if (idx < D_ * D_) {
        int a = idx / D_, c = idx % D_;
        float acc = 0.f;
        for (int m = 0; m < D_; m++) acc += bf(W_in, a * D_ + m) * bf(W_qkv, m * D_ + c);
        Wq_eff[idx] = acc;
    } else if (idx < 2 * D_ * D_) {
        int t = idx - D_ * D_, a = t / D_, c = t % D_;
        float acc = 0.f;
        for (int m = 0; m < D_; m++)
            acc += bf(W_in, (D_ + a) * D_ + m) * bf(W_qkv, (D_ + m) * D_ + c);
        Wk_eff[t] = acc;
    } else if (idx < 2 * D_ * D_ + D_) {
        int c = idx - 2 * D_ * D_;
        float acc = 0.f;
        for (int m = 0; m < D_; m++) acc += t_m[m] * bf(W_qkv, (2 * D_ + m) * D_ + c);
        wvl[c] = acc;
    }
}

// ---------------- K5: per-node projections T = W{q,k}{1,3} . x2[n]  (+bias folded) ----
__global__ __launch_bounds__(256) void nodeproj_kernel(
    const float* x2, const float* Wq_eff, const float* Wk_eff, const float* wvl,
    const float* bq_eff, const float* bk_eff, const float* sc,
    float* Tq1, float* Tq3, float* Tk1, float* Tk3, float* V13) {
    int n = blockIdx.x;  // 768 nodes
    __shared__ float sx[64];
    int tid = threadIdx.x;
    if (tid < 64) sx[tid] = x2[n * 64 + tid];
    __syncthreads();
    if (tid < D_) {
        int a = tid;
        float q1 = bq_eff[a], q3 = 0.f, k1 = bk_eff[a], k3 = 0.f;
        const float* wq = Wq_eff + a * D_;
        const float* wk = Wk_eff + a * D_;
        for (int c = 0; c < 64; c++) {
            float xv = sx[c];
            q1 += wq[c] * xv;       q3 += wq[128 + c] * xv;
            k1 += wk[c] * xv;       k3 += wk[128 + c] * xv;
        }
        Tq1[n * D_ + a] = q1; Tq3[n * D_ + a] = q3;
        Tk1[n * D_ + a] = k1; Tk3[n * D_ + a] = k3;
    } else if (tid == 192 || tid == 193) {
        int part = tid - 192;
        float v = (part == 0) ? sc[0] : 0.f;
        for (int c = 0; c < 64; c++) v += wvl[part * 128 + c] * sx[c];
        V13[part * NODES + n] = v;
    }
}

// ---------------- K6: per-edge mid-GEMM + combine -> Q,K (bf16), vl ----------------
__global__ __launch_bounds__(256) void qkvmid_kernel(
    const bf16* edge_attr, const bf16* W_ee, const bf16* b_ee,
    const float* Wq_eff, const float* Wk_eff, const float* wvl,
    const float* Tq1, const float* Tq3, const float* Tk1, const float* Tk3,
    const float* V13, bf16* Q, bf16* K, float* vl) {
    __shared__ unsigned short s_w2[192 * 136];  // [a][h] (q,k) bf16 pairs, row=136 shorts
    __shared__ float s_wk[32][68];              // wK per token (64 used; [64]=w,[65]=cls)
    __shared__ int s_ni[32], s_nj[32];
    int tid = threadIdx.x, base = blockIdx.x * 32;

    for (int idx = tid; idx < 192 * 64; idx += 256) {  // stage W2 as bf16 (q,k) pairs
        int a = idx >> 6, h = idx & 63;
        bf16 wq = __float2bfloat16(Wq_eff[a * D_ + 64 + h]);
        bf16 wk = __float2bfloat16(Wk_eff[a * D_ + 64 + h]);
        unsigned short uq = *reinterpret_cast<unsigned short*>(&wq);
        unsigned short uk = *reinterpret_cast<unsigned short*>(&wk);
        unsigned int pr = (unsigned int)uq | ((unsigned int)uk << 16);
        *reinterpret_cast<unsigned int*>(&s_w2[a * 136 + 2 * h]) = pr;
    }
    if (tid < 32) {  // token meta
        int kk_g = base + tid;
        int b = kk_g / S_, kk = kk_g % S_;
        int q = kk >> 1, cls = kk & 1;
        int i = (int)((1.0f + sqrtf(8.0f * (float)q + 1.0f)) * 0.5f);
        while (i * (i - 1) / 2 > q) --i;
        while ((i + 1) * i / 2 <= q) ++i;
        int j = q - i * (i - 1) / 2;
        s_ni[tid] = b * N_ + i; s_nj[tid] = b * N_ + j;
        int e = (b * PAIRS + i * 47 + j) * 2 + cls;
        s_wk[tid][64] = bf(edge_attr, e * 2);
        s_wk[tid][65] = (float)cls;
    }
    __syncthreads();
    for (int idx = tid; idx < 32 * 64; idx += 256) {  // wK = relu(edge-emb)
        int t = idx >> 6, h = idx & 63;
        int cls = (int)s_wk[t][65];
        float v = bf(W_ee, h * 3) * s_wk[t][64] + bf(W_ee, h * 3 + 1 + cls) + bf(b_ee, h);
        s_wk[t][h] = fmaxf(v, 0.f);
    }
    __syncthreads();
    int tok = tid >> 3, g = tid & 7;
    int ni = s_ni[tok], nj = s_nj[tok];
    long token = base + tok;
    float4v wkv[16];
    #pragma unroll
    for (int c = 0; c < 16; c++) wkv[c] = *(const float4v*)&s_wk[tok][c * 4];
    #pragma unroll 4
    for (int am = 0; am < 24; am++) {
        int a = g + 8 * am;  // stride-8 so the 8 g-rows hit 8 distinct bank quads
        float mq = 0.f, mk = 0.f;
        const unsigned short* wrow = &s_w2[a * 136];
        #pragma unroll
        for (int c = 0; c < 16; c++) {
            ushort8 w8 = *(const ushort8*)(wrow + c * 8);
            float4v w4 = wkv[c];
            mq += u2f(w8[0]) * w4.x + u2f(w8[2]) * w4.y + u2f(w8[4]) * w4.z + u2f(w8[6]) * w4.w;
            mk += u2f(w8[1]) * w4.x + u2f(w8[3]) * w4.y + u2f(w8[5]) * w4.z + u2f(w8[7]) * w4.w;
        }
        float qv = (Tq1[ni * D_ + a] + Tq3[nj * D_ + a] + mq) * QSCALE;
        float kv = Tk1[ni * D_ + a] + Tk3[nj * D_ + a] + mk;
        Q[token * D_ + a] = __float2bfloat16(qv);
        K[token * D_ + a] = __float2bfloat16(kv);
    }
    if (tid < 32) {
        float v = V13[s_ni[tid]] + V13[NODES + s_nj[tid]];
        for (int h = 0; h < 64; h++) v += wvl[64 + h] * s_wk[tid][h];
        vl[base + tid] = v;
    }
}

// ---------------- K7: MFMA flash attention (scalar value) ----------------
__device__ __forceinline__ void stage_k(const bf16* K, const float* vl, int b, int it,
                                        short* sk, float* svl, int tid) {
    #pragma unroll
    for (int r = 0; r < 6; r++) {
        int c = tid + r * 128;            // 768 chunks of 16B
        int row = c / 24, cc = c % 24;
        int key = it * 32 + row;
        int gk = b * S_ + (key < S_ ? key : S_ - 1);
        const uint4* src = (const uint4*)((const short*)K + (long)gk * D_ + cc * 8);
        *(uint4*)&sk[row * 200 + cc * 8] = *src;
    }
    if (tid < 32) {
        int key = it * 32 + tid;
        svl[tid] = (key < S_) ? vl[b * S_ + key] : 0.f;
    }
}

__global__ __launch_bounds__(128) void attn_kernel(const bf16* Q, const bf16* K,
                                                   const float* vl, const float* sc,
                                                   float* logit) {
    // XCD swizzle: blocks of the same batch stay on one XCD (K fits its L2)
    int x = blockIdx.x;                 // 576 blocks
    int rr = x & 7, s = x >> 3;         // s in 0..71
    int b = rr + 8 * (s >= 36);
    int qb = (s >= 36) ? s - 36 : s;    // 0..35
    int tid = threadIdx.x;
    int wave = tid >> 6, lane = tid & 63;
    int n5 = lane & 31, h5 = lane >> 5;
    int qt = qb * 2 + wave;             // 0..71 (valid < 71)
    bool qvalid = qt < QTILES;

    __shared__ short s_k[2][32 * 200];
    __shared__ float s_vl[2][32];

    short8 qf[12];
    {
        int qrow = b * S_ + qt * 32 + n5;
        if (qrow > B_ * S_ - 1) qrow = B_ * S_ - 1;
        const short* qp = (const short*)Q + (long)qrow * D_;
        #pragma unroll
        for (int kc = 0; kc < 12; kc++) qf[kc] = *(const short8*)(qp + kc * 16 + h5 * 8);
    }

    float mr[16], lr[16], ar[16];
    #pragma unroll
    for (int r = 0; r < 16; r++) { mr[r] = -3.0e38f; lr[r] = 0.f; ar[r] = 0.f; }

    stage_k(K, vl, b, 0, s_k[0], s_vl[0], tid);

    for (int it = 0; it < KITERS; ++it) {
        __syncthreads();
        if (it + 1 < KITERS)
            stage_k(K, vl, b, it + 1, s_k[(it + 1) & 1], s_vl[(it + 1) & 1], tid);
        const short* kb = s_k[it & 1];
        float16v c;
        #pragma unroll
        for (int r = 0; r < 16; r++) c[r] = 0.f;
        #pragma unroll
        for (int kc = 0; kc < 12; kc++) {
            short8 bfr = *(const short8*)(kb + n5 * 200 + kc * 16 + h5 * 8);
            c = __builtin_amdgcn_mfma_f32_32x32x16_bf16(qf[kc], bfr, c, 0, 0, 0);
        }
        float vlv = s_vl[it & 1][n5];
        bool kvalid = (it * 32 + n5) < S_;
        #pragma unroll
        for (int r = 0; r < 16; r++) {
            float sv = kvalid ? c[r] : -3.0e38f;   // scores already in log2 domain
            float mn = fmaxf(mr[r], sv);
            float al = __builtin_amdgcn_exp2f(mr[r] - mn);
            float p  = __builtin_amdgcn_exp2f(sv - mn);
            lr[r] = lr[r] * al + p;
            ar[r] = ar[r] * al + p * vlv;
            mr[r] = mn;
        }
    }

    if (qvalid) {
        #pragma unroll
        for (int r = 0; r < 16; r++) {
            float m = mr[r], l = lr[r], a = ar[r];
            #pragma unroll
            for (int off = 1; off < 32; off <<= 1) {
                float m2 = __shfl_xor(m, off, 64);
                float l2 = __shfl_xor(l, off, 64);
                float a2 = __shfl_xor(a, off, 64);
                float mn = fmaxf(m, m2);
                float e1 = __builtin_amdgcn_exp2f(m - mn);
                float e2 = __builtin_amdgcn_exp2f(m2 - mn);
                l = l * e1 + l2 * e2;
                a = a * e1 + a2 * e2;
                m = mn;
            }
            if (n5 == 0) {
                int qrow = qt * 32 + (r & 3) + 8 * (r >> 2) + 4 * h5;
                if (qrow < S_) logit[b * S_ + qrow] = sanitize(a / l + sc[1]);
            }
        }
    }
}

// ---------------- K8: pairing / argmin epilogue (fp32 d_out) ----------------
__global__ __launch_bounds__(256) void final_kernel(const float* logit, float* out) {
    int idx = blockIdx.x * 256 + threadIdx.x;
    if (idx >= B_ * SH) return;
    int b = idx / SH, p = idx % SH;
    int i = (int)((1.0f + sqrtf(8.0f * (float)p + 1.0f)) * 0.5f);
    while (i * (i - 1) / 2 > p) --i;
    while ((i + 1) * i / 2 <= p) ++i;
    int j = p - i * (i - 1) / 2;
    float l0 = sanitize(logit[b * S_ + 2 * p]), l1 = sanitize(logit[b * S_ + 2 * p + 1]);
    int ind = (l1 < l0) ? 1 : 0;
    float ef = ind ? l1 : l0;
    out[(b * SH + p) * 2 + 0] = (float)(b * N_ + i);
    out[(b * SH + p) * 2 + 1] = (float)(b * N_ + j);
    out[2 * B_ * SH + idx] = ef;
    out[2 * B_ * SH + B_ * SH + idx] = (float)ind;
}

extern "C" void kernel_launch(void* const* d_in, const int* in_sizes, int n_in,
                              void* d_out, int out_size, void* d_ws, size_t ws_size,
                              hipStream_t stream) {
    const bf16* x         = (const bf16*)d_in[0];
    const bf16* edge_attr = (const bf16*)d_in[2];
    const bf16* W_we   = (const bf16*)d_in[5];
    const bf16* b_we   = (const bf16*)d_in[6];
    const bf16* Wrel1  = (const bf16*)d_in[7];
    const bf16* brel1  = (const bf16*)d_in[8];
    const bf16* Wroot1 = (const bf16*)d_in[9];
    const bf16* Wrel2  = (const bf16*)d_in[10];
    const bf16* brel2  = (const bf16*)d_in[11];
    const bf16* Wroot2 = (const bf16*)d_in[12];
    const bf16* W_ee   = (const bf16*)d_in[13];
    const bf16* b_ee   = (const bf16*)d_in[14];
    const bf16* W_qkv  = (const bf16*)d_in[15];
    const bf16* b_qkv  = (const bf16*)d_in[16];
    const bf16* W_in   = (const bf16*)d_in[17];
    const bf16* b_in   = (const bf16*)d_in[18];
    const bf16* W_out  = (const bf16*)d_in[19];
    const bf16* b_out  = (const bf16*)d_in[20];
    const bf16* W_o    = (const bf16*)d_in[21];
    const bf16* b_o    = (const bf16*)d_in[22];

    float* w = (float*)d_ws;
    float* Wq_eff = w;                  // 36864
    float* Wk_eff = Wq_eff + 36864;     // 36864
    float* wvl    = Wk_eff + 36864;     // 192
    float* bq_eff = wvl + 192;
    float* bk_eff = bq_eff + 192;
    float* wo_eff = bk_eff + 192;
    float* t_m    = wo_eff + 192;
    float* sc     = t_m + 192;          // 64 (2 used)
    float* ws_sum = sc + 64;            // 36864
    float* x2     = ws_sum + 36864;     // 49152
    float* vl     = x2 + 49152;         // 36096
    float* logit  = vl + 36096;         // 36096
    bf16*  Q      = (bf16*)(logit + 36096);   // EK*192 bf16
    bf16*  K      = Q + (long)EK * D_;        // EK*192 bf16
    float* Tq1    = (float*)(K + (long)EK * D_);  // 147456
    float* Tq3    = Tq1 + NODES * D_;
    float* Tk1    = Tq3 + NODES * D_;
    float* Tk3    = Tk1 + NODES * D_;
    float* V13    = Tk3 + NODES * D_;   // 1536
    // total ~33 MB of 256 MB workspace

    edgew_kernel<<<(B_ * N_ * N_ + 255) / 256, 256, 0, stream>>>(edge_attr, W_we, b_we, ws_sum);
    graphconv_kernel<<<B_, 256, 0, stream>>>(ws_sum, x, Wrel1, brel1, Wroot1, Wrel2, brel2,
                                             Wroot2, x2);
    compose_a<<<1, 256, 0, stream>>>(W_o, b_o, W_out, b_out, W_in, b_in, b_qkv, wo_eff, bq_eff,
                                     bk_eff, t_m, sc);
    compose_b<<<(2 * D_ * D_ + D_ + 255) / 256, 256, 0, stream>>>(W_in, W_qkv, t_m, Wq_eff,
                                                                  Wk_eff, wvl);
    nodeproj_kernel<<<NODES, 256, 0, stream>>>(x2, Wq_eff, Wk_eff, wvl, bq_eff, bk_eff, sc,
                                               Tq1, Tq3, Tk1, Tk3, V13);
    qkvmid_kernel<<<EK / 32, 256, 0, stream>>>(edge_attr, W_ee, b_ee, Wq_eff, Wk_eff, wvl,
                                               Tq1, Tq3, Tk1, Tk3, V13, Q, K, vl);
    attn_kernel<<<576, 128, 0, stream>>>(Q, K, vl, sc, logit);
    final_kernel<<<(B_ * SH + 255) / 256, 256, 0, stream>>>(logit, (float*)d_out);
}

// Round 8
// 329.185 us; speedup vs baseline: 11.0919x; 1.1741x over previous
//
#include <hip/hip_runtime.h>
#include <hip/hip_bf16.h>

typedef __hip_bfloat16 bf16;
typedef __attribute__((ext_vector_type(8))) short short8;
typedef __attribute__((ext_vector_type(8))) unsigned short ushort8;
typedef __attribute__((ext_vector_type(16))) float float16v;
typedef __attribute__((ext_vector_type(4))) float float4v;

#define B_     16
#define N_     48
#define NODES  768
#define PAIRS  2256
#define EK     36096
#define S_     2256
#define SH     1128
#define D_     192
#define KITERS 71
#define QTILES 71
#define QSCALE 0.10411754f  // log2(e)/sqrt(192): folded into Q at store

__device__ __forceinline__ float bf(const bf16* p, int i) { return __bfloat162float(p[i]); }
__device__ __forceinline__ float u2f(unsigned short u) {
    return __uint_as_float(((unsigned int)u) << 16);
}
__device__ __forceinline__ float sanitize(float v) {
    if (v > -1e4f && v < 1e4f) return v;
    if (v >= 1e4f) return 1e4f;
    if (v <= -1e4f) return -1e4f;
    return 0.f;  // NaN
}

// ---------------- K1: fused edge-weight + 2-layer GraphConv, one block/batch ----------
__global__ __launch_bounds__(256) void graphconv_kernel(
    const bf16* edge_attr, const bf16* W_we, const bf16* b_we, const bf16* x,
    const bf16* Wrel1, const bf16* brel1, const bf16* Wroot1,
    const bf16* Wrel2, const bf16* brel2, const bf16* Wroot2, float* x2out) {
    int b = blockIdx.x, tid = threadIdx.x;
    __shared__ float s_ws[N_ * N_];
    __shared__ float s_x[N_ * 5], s_agg1[N_ * 5];
    __shared__ float s_x1[N_ * 32], s_agg2[N_ * 32];
    float we0 = bf(W_we, 0), we1 = bf(W_we, 1), we2 = bf(W_we, 2), bw = bf(b_we, 0);
    for (int idx = tid; idx < N_ * N_; idx += 256) {
        int i = idx / N_, j = idx % N_;
        float v = 0.f;
        if (i != j) {
            int p = i * 47 + (j < i ? j : j - 1);
            int e = (b * PAIRS + p) * 2;
            float w0 = fmaxf(we0 * bf(edge_attr, (e + 0) * 2) + we1 + bw, 0.f);
            float w1 = fmaxf(we0 * bf(edge_attr, (e + 1) * 2) + we2 + bw, 0.f);
            v = w0 + w1;
        }
        s_ws[idx] = v;
    }
    for (int idx = tid; idx < N_ * 5; idx += 256) s_x[idx] = bf(x, b * N_ * 5 + idx);
    __syncthreads();
    if (tid < 240) {
        int j = tid / 5, f = tid % 5;
        float a = 0.f;
        for (int i = 0; i < N_; i++) a += s_ws[i * N_ + j] * s_x[i * 5 + f];
        s_agg1[tid] = a;
    }
    __syncthreads();
    for (int o = tid; o < N_ * 32; o += 256) {
        int j = o >> 5, h = o & 31;
        float a = bf(brel1, h);
        for (int f = 0; f < 5; f++)
            a += bf(Wrel1, h * 5 + f) * s_agg1[j * 5 + f] + bf(Wroot1, h * 5 + f) * s_x[j * 5 + f];
        s_x1[o] = fmaxf(a, 0.f);
    }
    __syncthreads();
    for (int o = tid; o < N_ * 32; o += 256) {
        int j = o >> 5, h = o & 31;
        float a = 0.f;
        for (int i = 0; i < N_; i++) a += s_ws[i * N_ + j] * s_x1[i * 32 + h];
        s_agg2[o] = a;
    }
    __syncthreads();
    for (int o = tid; o < N_ * 64; o += 256) {
        int j = o >> 6, h2 = o & 63;
        float a = bf(brel2, h2);
        for (int h1 = 0; h1 < 32; h1++)
            a += bf(Wrel2, h2 * 32 + h1) * s_agg2[j * 32 + h1] +
                 bf(Wroot2, h2 * 32 + h1) * s_x1[j * 32 + h1];
        x2out[(b * N_ + j) * 64 + h2] = fmaxf(a, 0.f);
    }
}

// ---------------- K2: compose stage A1 — wave-parallel dot products ----------------
__global__ __launch_bounds__(256) void compose_a1(
    const bf16* W_o, const bf16* b_o, const bf16* W_out, const bf16* b_out,
    const bf16* W_in, const bf16* b_in, const bf16* b_qkv,
    float* wo_eff, float* bq_eff, float* bk_eff, float* bv_eff, float* sc) {
    int a = blockIdx.x;  // 0..191 outputs; block 192 = co
    int wave = threadIdx.x >> 6, lane = threadIdx.x & 63;
    float partial = 0.f;
    if (a < 192) {
        if (wave == 0) {
            for (int m = lane; m < 192; m += 64) partial += bf(W_o, m) * bf(W_out, m * 192 + a);
        } else {
            int row = (wave - 1) * 192 + a;
            for (int m = lane; m < 192; m += 64)
                partial += bf(W_in, row * 192 + m) * bf(b_qkv, (wave - 1) * 192 + m);
        }
    } else if (wave == 0) {
        for (int m = lane; m < 192; m += 64) partial += bf(W_o, m) * bf(b_out, m);
    }
    for (int off = 32; off; off >>= 1) partial += __shfl_xor(partial, off, 64);
    if (lane == 0) {
        if (a < 192) {
            if (wave == 0) wo_eff[a] = partial;
            else if (wave == 1) bq_eff[a] = partial + bf(b_in, a);
            else if (wave == 2) bk_eff[a] = partial + bf(b_in, 192 + a);
            else bv_eff[a] = partial + bf(b_in, 384 + a);
        } else if (wave == 0) sc[1] = partial + bf(b_o, 0);
    }
}

// ---------------- K3: compose stage A2 — t_m (needs wo_eff), bvl ----------------
__global__ __launch_bounds__(256) void compose_a2(const bf16* W_in, const float* wo_eff,
                                                  const float* bv_eff, float* t_m, float* sc) {
    int w = blockIdx.x * 4 + (threadIdx.x >> 6);
    int lane = threadIdx.x & 63;
    float partial = 0.f;
    if (w < 192) {
        for (int aa = lane; aa < 192; aa += 64)
            partial += wo_eff[aa] * bf(W_in, (384 + aa) * 192 + w);
    } else if (w == 192) {
        for (int aa = lane; aa < 192; aa += 64) partial += wo_eff[aa] * bv_eff[aa];
    }
    for (int off = 32; off; off >>= 1) partial += __shfl_xor(partial, off, 64);
    if (lane == 0) {
        if (w < 192) t_m[w] = partial;
        else if (w == 192) sc[0] = partial;
    }
}

// ---------------- K4: compose stage B (matrices) ----------------
__global__ __launch_bounds__(256) void compose_b(const bf16* W_in, const bf16* W_qkv,
                                                 const float* t_m, float* Wq_eff,
                                                 float* Wk_eff, float* wvl) {
    int idx = blockIdx.x * 256 + threadIdx.x;
    if (idx < D_ * D_) {
        int a = idx / D_, c = idx % D_;
        float acc = 0.f;
        for (int m = 0; m < D_; m++) acc += bf(W_in, a * D_ + m) * bf(W_qkv, m * D_ + c);
        Wq_eff[idx] = acc;
    } else if (idx < 2 * D_ * D_) {
        int t = idx - D_ * D_, a = t / D_, c = t % D_;
        float acc = 0.f;
        for (int m = 0; m < D_; m++)
            acc += bf(W_in, (D_ + a) * D_ + m) * bf(W_qkv, (D_ + m) * D_ + c);
        Wk_eff[t] = acc;
    } else if (idx < 2 * D_ * D_ + D_) {
        int c = idx - 2 * D_ * D_;
        float acc = 0.f;
        for (int m = 0; m < D_; m++) acc += t_m[m] * bf(W_qkv, (2 * D_ + m) * D_ + c);
        wvl[c] = acc;
    }
}

// ---------------- K5: per-node projections ----------------
__global__ __launch_bounds__(256) void nodeproj_kernel(
    const float* x2, const float* Wq_eff, const float* Wk_eff, const float* wvl,
    const float* bq_eff, const float* bk_eff, const float* sc,
    float* Tq1, float* Tq3, float* Tk1, float* Tk3, float* V13) {
    int n = blockIdx.x;
    __shared__ float sx[64];
    int tid = threadIdx.x;
    if (tid < 64) sx[tid] = x2[n * 64 + tid];
    __syncthreads();
    if (tid < D_) {
        int a = tid;
        float q1 = bq_eff[a], q3 = 0.f, k1 = bk_eff[a], k3 = 0.f;
        const float* wq = Wq_eff + a * D_;
        const float* wk = Wk_eff + a * D_;
        for (int c = 0; c < 64; c++) {
            float xv = sx[c];
            q1 += wq[c] * xv;       q3 += wq[128 + c] * xv;
            k1 += wk[c] * xv;       k3 += wk[128 + c] * xv;
        }
        Tq1[n * D_ + a] = q1; Tq3[n * D_ + a] = q3;
        Tk1[n * D_ + a] = k1; Tk3[n * D_ + a] = k3;
    } else if (tid == 192 || tid == 193) {
        int part = tid - 192;
        float v = (part == 0) ? sc[0] : 0.f;
        for (int c = 0; c < 64; c++) v += wvl[part * 128 + c] * sx[c];
        V13[part * NODES + n] = v;
    }
}

// ---------------- K6: per-edge mid-GEMM (two-phase W2 staging) -> Q,K,vl ----------
__global__ __launch_bounds__(256) void qkvmid_kernel(
    const bf16* edge_attr, const bf16* W_ee, const bf16* b_ee,
    const float* Wq_eff, const float* Wk_eff, const float* wvl,
    const float* Tq1, const float* Tq3, const float* Tk1, const float* Tk3,
    const float* V13, bf16* Q, bf16* K, float* vl) {
    __shared__ unsigned short s_w2[96 * 136];   // half of W2 (q,k) bf16 pairs: 26.1 KB
    __shared__ float s_wk[32][68];
    __shared__ int s_ni[32], s_nj[32];
    int tid = threadIdx.x, base = blockIdx.x * 32;

    if (tid < 32) {
        int kk_g = base + tid;
        int b = kk_g / S_, kk = kk_g % S_;
        int q = kk >> 1, cls = kk & 1;
        int i = (int)((1.0f + sqrtf(8.0f * (float)q + 1.0f)) * 0.5f);
        while (i * (i - 1) / 2 > q) --i;
        while ((i + 1) * i / 2 <= q) ++i;
        int j = q - i * (i - 1) / 2;
        s_ni[tid] = b * N_ + i; s_nj[tid] = b * N_ + j;
        int e = (b * PAIRS + i * 47 + j) * 2 + cls;
        s_wk[tid][64] = bf(edge_attr, e * 2);
        s_wk[tid][65] = (float)cls;
    }
    __syncthreads();
    for (int idx = tid; idx < 32 * 64; idx += 256) {
        int t = idx >> 6, h = idx & 63;
        int cls = (int)s_wk[t][65];
        float v = bf(W_ee, h * 3) * s_wk[t][64] + bf(W_ee, h * 3 + 1 + cls) + bf(b_ee, h);
        s_wk[t][h] = fmaxf(v, 0.f);
    }
    __syncthreads();
    int tok = tid >> 3, g = tid & 7;
    int ni = s_ni[tok], nj = s_nj[tok];
    long token = base + tok;
    float4v wkv[16];
    #pragma unroll
    for (int c = 0; c < 16; c++) wkv[c] = *(const float4v*)&s_wk[tok][c * 4];

    for (int ph = 0; ph < 2; ph++) {
        for (int idx = tid; idx < 96 * 64; idx += 256) {
            int al = idx >> 6, h = idx & 63;
            int a = ph * 96 + al;
            bf16 wq = __float2bfloat16(Wq_eff[a * D_ + 64 + h]);
            bf16 wk = __float2bfloat16(Wk_eff[a * D_ + 64 + h]);
            unsigned short uq = *reinterpret_cast<unsigned short*>(&wq);
            unsigned short uk = *reinterpret_cast<unsigned short*>(&wk);
            unsigned int pr = (unsigned int)uq | ((unsigned int)uk << 16);
            *reinterpret_cast<unsigned int*>(&s_w2[al * 136 + 2 * h]) = pr;
        }
        __syncthreads();
        #pragma unroll 4
        for (int am = 0; am < 12; am++) {
            int al = g + 8 * am;
            int a = ph * 96 + al;
            float mq = 0.f, mk = 0.f;
            const unsigned short* wrow = &s_w2[al * 136];
            #pragma unroll
            for (int c = 0; c < 16; c++) {
                ushort8 w8 = *(const ushort8*)(wrow + c * 8);
                float4v w4 = wkv[c];
                mq += u2f(w8[0]) * w4.x + u2f(w8[2]) * w4.y + u2f(w8[4]) * w4.z + u2f(w8[6]) * w4.w;
                mk += u2f(w8[1]) * w4.x + u2f(w8[3]) * w4.y + u2f(w8[5]) * w4.z + u2f(w8[7]) * w4.w;
            }
            float qv = (Tq1[ni * D_ + a] + Tq3[nj * D_ + a] + mq) * QSCALE;
            float kv = Tk1[ni * D_ + a] + Tk3[nj * D_ + a] + mk;
            Q[token * D_ + a] = __float2bfloat16(qv);
            K[token * D_ + a] = __float2bfloat16(kv);
        }
        __syncthreads();
    }
    if (tid < 32) {
        float v = V13[s_ni[tid]] + V13[NODES + s_nj[tid]];
        for (int h = 0; h < 64; h++) v += wvl[64 + h] * s_wk[tid][h];
        vl[base + tid] = v;
    }
}

// ---------------- K7: split-K MFMA flash attention -> partials ----------------
__device__ __forceinline__ void stage_k(const bf16* K, const float* vl, int b, int it,
                                        short* sk, float* svl, int tid) {
    #pragma unroll
    for (int r = 0; r < 3; r++) {
        int c = tid + r * 256;            // 768 chunks of 16B
        int row = c / 24, cc = c % 24;
        int key = it * 32 + row;
        int gk = b * S_ + (key < S_ ? key : S_ - 1);
        const uint4* src = (const uint4*)((const short*)K + (long)gk * D_ + cc * 8);
        *(uint4*)&sk[row * 200 + cc * 8] = *src;
    }
    if (tid < 32) {
        int key = it * 32 + tid;
        svl[tid] = (key < S_) ? vl[b * S_ + key] : 0.f;
    }
}

__global__ __launch_bounds__(256) void attn_kernel(const bf16* Q, const bf16* K,
                                                   const float* vl, float* part) {
    // 1152 blocks: XCD swizzle keeps each batch's K in one XCD's L2
    int x = blockIdx.x;
    int rr = x & 7, rest = x >> 3;      // rest 0..143
    int half = rest >= 72;
    int s = rest - 72 * half;
    int b = rr + 8 * half;
    int chunk = s & 3, qb = s >> 2;     // qb 0..17
    int tid = threadIdx.x;
    int wave = tid >> 6, lane = tid & 63;
    int n5 = lane & 31, h5 = lane >> 5;
    int qt = qb * 4 + wave;             // 0..71 (71 invalid)
    bool qvalid = qt < QTILES;
    int t0 = chunk * 18, t1 = (chunk == 3) ? KITERS : (chunk * 18 + 18);

    __shared__ short s_k[2][32 * 200];
    __shared__ float s_vl[2][32];

    short8 qf[12];
    {
        int qrow = b * S_ + qt * 32 + n5;
        if (qrow > B_ * S_ - 1) qrow = B_ * S_ - 1;
        const short* qp = (const short*)Q + (long)qrow * D_;
        #pragma unroll
        for (int kc = 0; kc < 12; kc++) qf[kc] = *(const short8*)(qp + kc * 16 + h5 * 8);
    }

    float mr[16], lr[16], ar[16];
    #pragma unroll
    for (int r = 0; r < 16; r++) { mr[r] = -3.0e38f; lr[r] = 0.f; ar[r] = 0.f; }

    stage_k(K, vl, b, t0, s_k[0], s_vl[0], tid);

    for (int it = t0; it < t1; ++it) {
        int buf = (it - t0) & 1;
        __syncthreads();
        if (it + 1 < t1)
            stage_k(K, vl, b, it + 1, s_k[buf ^ 1], s_vl[buf ^ 1], tid);
        const short* kb = s_k[buf];
        float16v c;
        #pragma unroll
        for (int r = 0; r < 16; r++) c[r] = 0.f;
        #pragma unroll
        for (int kc = 0; kc < 12; kc++) {
            short8 bfr = *(const short8*)(kb + n5 * 200 + kc * 16 + h5 * 8);
            c = __builtin_amdgcn_mfma_f32_32x32x16_bf16(qf[kc], bfr, c, 0, 0, 0);
        }
        float vlv = s_vl[buf][n5];
        bool kvalid = (it * 32 + n5) < S_;
        #pragma unroll
        for (int r = 0; r < 16; r++) {
            float sv = kvalid ? c[r] : -3.0e38f;   // scores in log2 domain
            float mn = fmaxf(mr[r], sv);
            float al = __builtin_amdgcn_exp2f(mr[r] - mn);
            float p  = __builtin_amdgcn_exp2f(sv - mn);
            lr[r] = lr[r] * al + p;
            ar[r] = ar[r] * al + p * vlv;
            mr[r] = mn;
        }
    }

    if (qvalid) {
        #pragma unroll
        for (int r = 0; r < 16; r++) {
            float m = mr[r], l = lr[r], a = ar[r];
            #pragma unroll
            for (int off = 1; off < 32; off <<= 1) {
                float m2 = __shfl_xor(m, off, 64);
                float l2 = __shfl_xor(l, off, 64);
                float a2 = __shfl_xor(a, off, 64);
                float mn = fmaxf(m, m2);
                float e1 = __builtin_amdgcn_exp2f(m - mn);
                float e2 = __builtin_amdgcn_exp2f(m2 - mn);
                l = l * e1 + l2 * e2;
                a = a * e1 + a2 * e2;
                m = mn;
            }
            if (n5 == 0) {
                int qrow = qt * 32 + (r & 3) + 8 * (r >> 2) + 4 * h5;
                if (qrow < S_) {
                    float4v pv = {m, l, a, 0.f};
                    *(float4v*)&part[((long)(b * S_ + qrow) * 4 + chunk) * 4] = pv;
                }
            }
        }
    }
}

// ---------------- K8: merge partials + pairing/argmin (fp32 d_out) ----------------
__global__ __launch_bounds__(256) void final_kernel(const float* part, const float* sc,
                                                    float* out) {
    int idx = blockIdx.x * 256 + threadIdx.x;
    if (idx >= B_ * SH) return;
    int b = idx / SH, p = idx % SH;
    int i = (int)((1.0f + sqrtf(8.0f * (float)p + 1.0f)) * 0.5f);
    while (i * (i - 1) / 2 > p) --i;
    while ((i + 1) * i / 2 <= p) ++i;
    int j = p - i * (i - 1) / 2;
    float co = sc[1];
    float lg[2];
    #pragma unroll
    for (int t = 0; t < 2; t++) {
        long g = (long)b * S_ + 2 * p + t;
        float m = -3.0e38f, l = 0.f, a = 0.f;
        #pragma unroll
        for (int c = 0; c < 4; c++) {
            float4v pc = *(const float4v*)&part[(g * 4 + c) * 4];
            float mn = fmaxf(m, pc.x);
            float e1 = __builtin_amdgcn_exp2f(m - mn);
            float e2 = __builtin_amdgcn_exp2f(pc.x - mn);
            l = l * e1 + pc.y * e2;
            a = a * e1 + pc.z * e2;
            m = mn;
        }
        lg[t] = sanitize(a / l + co);
    }
    int ind = (lg[1] < lg[0]) ? 1 : 0;
    float ef = ind ? lg[1] : lg[0];
    out[(b * SH + p) * 2 + 0] = (float)(b * N_ + i);
    out[(b * SH + p) * 2 + 1] = (float)(b * N_ + j);
    out[2 * B_ * SH + idx] = ef;
    out[2 * B_ * SH + B_ * SH + idx] = (float)ind;
}

extern "C" void kernel_launch(void* const* d_in, const int* in_sizes, int n_in,
                              void* d_out, int out_size, void* d_ws, size_t ws_size,
                              hipStream_t stream) {
    const bf16* x         = (const bf16*)d_in[0];
    const bf16* edge_attr = (const bf16*)d_in[2];
    const bf16* W_we   = (const bf16*)d_in[5];
    const bf16* b_we   = (const bf16*)d_in[6];
    const bf16* Wrel1  = (const bf16*)d_in[7];
    const bf16* brel1  = (const bf16*)d_in[8];
    const bf16* Wroot1 = (const bf16*)d_in[9];
    const bf16* Wrel2  = (const bf16*)d_in[10];
    const bf16* brel2  = (const bf16*)d_in[11];
    const bf16* Wroot2 = (const bf16*)d_in[12];
    const bf16* W_ee   = (const bf16*)d_in[13];
    const bf16* b_ee   = (const bf16*)d_in[14];
    const bf16* W_qkv  = (const bf16*)d_in[15];
    const bf16* b_qkv  = (const bf16*)d_in[16];
    const bf16* W_in   = (const bf16*)d_in[17];
    const bf16* b_in   = (const bf16*)d_in[18];
    const bf16* W_out  = (const bf16*)d_in[19];
    const bf16* b_out  = (const bf16*)d_in[20];
    const bf16* W_o    = (const bf16*)d_in[21];
    const bf16* b_o    = (const bf16*)d_in[22];

    float* w = (float*)d_ws;
    float* Wq_eff = w;                  // 36864
    float* Wk_eff = Wq_eff + 36864;     // 36864
    float* wvl    = Wk_eff + 36864;     // 192
    float* bq_eff = wvl + 192;
    float* bk_eff = bq_eff + 192;
    float* bv_eff = bk_eff + 192;
    float* wo_eff = bv_eff + 192;
    float* t_m    = wo_eff + 192;
    float* sc     = t_m + 192;          // 64 (2 used)
    float* x2     = sc + 64;            // 49152
    float* vl     = x2 + 49152;         // 36096
    float* part   = vl + 36096;         // 36096*4*4 = 577536 (16B aligned)
    bf16*  Q      = (bf16*)(part + 577536);   // EK*192 bf16
    bf16*  K      = Q + (long)EK * D_;        // EK*192 bf16
    float* Tq1    = (float*)(K + (long)EK * D_);  // 147456 x4
    float* Tq3    = Tq1 + NODES * D_;
    float* Tk1    = Tq3 + NODES * D_;
    float* Tk3    = Tk1 + NODES * D_;
    float* V13    = Tk3 + NODES * D_;   // 1536
    // total ~36 MB of 256 MB workspace

    graphconv_kernel<<<B_, 256, 0, stream>>>(edge_attr, W_we, b_we, x, Wrel1, brel1, Wroot1,
                                             Wrel2, brel2, Wroot2, x2);
    compose_a1<<<193, 256, 0, stream>>>(W_o, b_o, W_out, b_out, W_in, b_in, b_qkv,
                                        wo_eff, bq_eff, bk_eff, bv_eff, sc);
    compose_a2<<<49, 256, 0, stream>>>(W_in, wo_eff, bv_eff, t_m, sc);
    compose_b<<<(2 * D_ * D_ + D_ + 255) / 256, 256, 0, stream>>>(W_in, W_qkv, t_m, Wq_eff,
                                                                  Wk_eff, wvl);
    nodeproj_kernel<<<NODES, 256, 0, stream>>>(x2, Wq_eff, Wk_eff, wvl, bq_eff, bk_eff, sc,
                                               Tq1, Tq3, Tk1, Tk3, V13);
    qkvmid_kernel<<<EK / 32, 256, 0, stream>>>(edge_attr, W_ee, b_ee, Wq_eff, Wk_eff, wvl,
                                               Tq1, Tq3, Tk1, Tk3, V13, Q, K, vl);
    attn_kernel<<<1152, 256, 0, stream>>>(Q, K, vl, part);
    final_kernel<<<(B_ * SH + 255) / 256, 256, 0, stream>>>(part, sc, (float*)d_out);
}

// Round 9
// 326.373 us; speedup vs baseline: 11.1875x; 1.0086x over previous
//
#include <hip/hip_runtime.h>
#include <hip/hip_bf16.h>

typedef __hip_bfloat16 bf16;
typedef __attribute__((ext_vector_type(8))) short short8;
typedef __attribute__((ext_vector_type(8))) unsigned short ushort8;
typedef __attribute__((ext_vector_type(16))) float float16v;
typedef __attribute__((ext_vector_type(4))) float float4v;
typedef __attribute__((ext_vector_type(2))) float float2v;

#define B_     16
#define N_     48
#define NODES  768
#define PAIRS  2256
#define EK     36096
#define S_     2256
#define SH     1128
#define D_     192
#define KITERS 71
#define QTILES 71
#define QSCALE 0.10411754f  // log2(e)/sqrt(192): folded into Q at store

__device__ __forceinline__ float bf(const bf16* p, int i) { return __bfloat162float(p[i]); }
__device__ __forceinline__ float u2f(unsigned short u) {
    return __uint_as_float(((unsigned int)u) << 16);
}
__device__ __forceinline__ float sanitize(float v) {
    if (v > -1e4f && v < 1e4f) return v;
    if (v >= 1e4f) return 1e4f;
    if (v <= -1e4f) return -1e4f;
    return 0.f;  // NaN
}

// ---------------- K1: fused edge-weight + 2-layer GraphConv, one block/batch ----------
__global__ __launch_bounds__(256) void graphconv_kernel(
    const bf16* edge_attr, const bf16* W_we, const bf16* b_we, const bf16* x,
    const bf16* Wrel1, const bf16* brel1, const bf16* Wroot1,
    const bf16* Wrel2, const bf16* brel2, const bf16* Wroot2, float* x2out) {
    int b = blockIdx.x, tid = threadIdx.x;
    __shared__ float s_ws[N_ * N_];
    __shared__ float s_x[N_ * 5], s_agg1[N_ * 5];
    __shared__ float s_x1[N_ * 32], s_agg2[N_ * 32];
    float we0 = bf(W_we, 0), we1 = bf(W_we, 1), we2 = bf(W_we, 2), bw = bf(b_we, 0);
    for (int idx = tid; idx < N_ * N_; idx += 256) {
        int i = idx / N_, j = idx % N_;
        float v = 0.f;
        if (i != j) {
            int p = i * 47 + (j < i ? j : j - 1);
            int e = (b * PAIRS + p) * 2;
            float w0 = fmaxf(we0 * bf(edge_attr, (e + 0) * 2) + we1 + bw, 0.f);
            float w1 = fmaxf(we0 * bf(edge_attr, (e + 1) * 2) + we2 + bw, 0.f);
            v = w0 + w1;
        }
        s_ws[idx] = v;
    }
    for (int idx = tid; idx < N_ * 5; idx += 256) s_x[idx] = bf(x, b * N_ * 5 + idx);
    __syncthreads();
    if (tid < 240) {
        int j = tid / 5, f = tid % 5;
        float a = 0.f;
        for (int i = 0; i < N_; i++) a += s_ws[i * N_ + j] * s_x[i * 5 + f];
        s_agg1[tid] = a;
    }
    __syncthreads();
    for (int o = tid; o < N_ * 32; o += 256) {
        int j = o >> 5, h = o & 31;
        float a = bf(brel1, h);
        for (int f = 0; f < 5; f++)
            a += bf(Wrel1, h * 5 + f) * s_agg1[j * 5 + f] + bf(Wroot1, h * 5 + f) * s_x[j * 5 + f];
        s_x1[o] = fmaxf(a, 0.f);
    }
    __syncthreads();
    for (int o = tid; o < N_ * 32; o += 256) {
        int j = o >> 5, h = o & 31;
        float a = 0.f;
        for (int i = 0; i < N_; i++) a += s_ws[i * N_ + j] * s_x1[i * 32 + h];
        s_agg2[o] = a;
    }
    __syncthreads();
    for (int o = tid; o < N_ * 64; o += 256) {
        int j = o >> 6, h2 = o & 63;
        float a = bf(brel2, h2);
        for (int h1 = 0; h1 < 32; h1++)
            a += bf(Wrel2, h2 * 32 + h1) * s_agg2[j * 32 + h1] +
                 bf(Wroot2, h2 * 32 + h1) * s_x1[j * 32 + h1];
        x2out[(b * N_ + j) * 64 + h2] = fmaxf(a, 0.f);
    }
}

// ---------------- K2: compose stage A1 — wave-parallel dot products ----------------
__global__ __launch_bounds__(256) void compose_a1(
    const bf16* W_o, const bf16* b_o, const bf16* W_out, const bf16* b_out,
    const bf16* W_in, const bf16* b_in, const bf16* b_qkv,
    float* wo_eff, float* bq_eff, float* bk_eff, float* bv_eff, float* sc) {
    int a = blockIdx.x;  // 0..191 outputs; block 192 = co
    int wave = threadIdx.x >> 6, lane = threadIdx.x & 63;
    float partial = 0.f;
    if (a < 192) {
        if (wave == 0) {
            for (int m = lane; m < 192; m += 64) partial += bf(W_o, m) * bf(W_out, m * 192 + a);
        } else {
            int row = (wave - 1) * 192 + a;
            for (int m = lane; m < 192; m += 64)
                partial += bf(W_in, row * 192 + m) * bf(b_qkv, (wave - 1) * 192 + m);
        }
    } else if (wave == 0) {
        for (int m = lane; m < 192; m += 64) partial += bf(W_o, m) * bf(b_out, m);
    }
    for (int off = 32; off; off >>= 1) partial += __shfl_xor(partial, off, 64);
    if (lane == 0) {
        if (a < 192) {
            if (wave == 0) wo_eff[a] = partial;
            else if (wave == 1) bq_eff[a] = partial + bf(b_in, a);
            else if (wave == 2) bk_eff[a] = partial + bf(b_in, 192 + a);
            else bv_eff[a] = partial + bf(b_in, 384 + a);
        } else if (wave == 0) sc[1] = partial + bf(b_o, 0);
    }
}

// ---------------- K3: compose stage A2 — t_m (needs wo_eff), bvl ----------------
__global__ __launch_bounds__(256) void compose_a2(const bf16* W_in, const float* wo_eff,
                                                  const float* bv_eff, float* t_m, float* sc) {
    int w = blockIdx.x * 4 + (threadIdx.x >> 6);
    int lane = threadIdx.x & 63;
    float partial = 0.f;
    if (w < 192) {
        for (int aa = lane; aa < 192; aa += 64)
            partial += wo_eff[aa] * bf(W_in, (384 + aa) * 192 + w);
    } else if (w == 192) {
        for (int aa = lane; aa < 192; aa += 64) partial += wo_eff[aa] * bv_eff[aa];
    }
    for (int off = 32; off; off >>= 1) partial += __shfl_xor(partial, off, 64);
    if (lane == 0) {
        if (w < 192) t_m[w] = partial;
        else if (w == 192) sc[0] = partial;
    }
}

// ---------------- K4: compose stage B (matrices) ----------------
__global__ __launch_bounds__(256) void compose_b(const bf16* W_in, const bf16* W_qkv,
                                                 const float* t_m, float* Wq_eff,
                                                 float* Wk_eff, float* wvl) {
    int idx = blockIdx.x * 256 + threadIdx.x;
    if (idx < D_ * D_) {
        int a = idx / D_, c = idx % D_;
        float acc = 0.f;
        for (int m = 0; m < D_; m++) acc += bf(W_in, a * D_ + m) * bf(W_qkv, m * D_ + c);
        Wq_eff[idx] = acc;
    } else if (idx < 2 * D_ * D_) {
        int t = idx - D_ * D_, a = t / D_, c = t % D_;
        float acc = 0.f;
        for (int m = 0; m < D_; m++)
            acc += bf(W_in, (D_ + a) * D_ + m) * bf(W_qkv, (D_ + m) * D_ + c);
        Wk_eff[t] = acc;
    } else if (idx < 2 * D_ * D_ + D_) {
        int c = idx - 2 * D_ * D_;
        float acc = 0.f;
        for (int m = 0; m < D_; m++) acc += t_m[m] * bf(W_qkv, (2 * D_ + m) * D_ + c);
        wvl[c] = acc;
    }
}

// ---------------- K5: per-node projections ----------------
__global__ __launch_bounds__(256) void nodeproj_kernel(
    const float* x2, const float* Wq_eff, const float* Wk_eff, const float* wvl,
    const float* bq_eff, const float* bk_eff, const float* sc,
    float* Tq1, float* Tq3, float* Tk1, float* Tk3, float* V13) {
    int n = blockIdx.x;
    __shared__ float sx[64];
    int tid = threadIdx.x;
    if (tid < 64) sx[tid] = x2[n * 64 + tid];
    __syncthreads();
    if (tid < D_) {
        int a = tid;
        float q1 = bq_eff[a], q3 = 0.f, k1 = bk_eff[a], k3 = 0.f;
        const float* wq = Wq_eff + a * D_;
        const float* wk = Wk_eff + a * D_;
        for (int c = 0; c < 64; c++) {
            float xv = sx[c];
            q1 += wq[c] * xv;       q3 += wq[128 + c] * xv;
            k1 += wk[c] * xv;       k3 += wk[128 + c] * xv;
        }
        Tq1[n * D_ + a] = q1; Tq3[n * D_ + a] = q3;
        Tk1[n * D_ + a] = k1; Tk3[n * D_ + a] = k3;
    } else if (tid == 192 || tid == 193) {
        int part = tid - 192;
        float v = (part == 0) ? sc[0] : 0.f;
        for (int c = 0; c < 64; c++) v += wvl[part * 128 + c] * sx[c];
        V13[part * NODES + n] = v;
    }
}

// ---------------- K6: per-edge mid-GEMM (two-phase W2 staging) -> Q,K,vl ----------
__global__ __launch_bounds__(256) void qkvmid_kernel(
    const bf16* edge_attr, const bf16* W_ee, const bf16* b_ee,
    const float* Wq_eff, const float* Wk_eff, const float* wvl,
    const float* Tq1, const float* Tq3, const float* Tk1, const float* Tk3,
    const float* V13, bf16* Q, bf16* K, float* vl) {
    __shared__ unsigned short s_w2[96 * 136];
    __shared__ float s_wk[32][68];
    __shared__ int s_ni[32], s_nj[32];
    int tid = threadIdx.x, base = blockIdx.x * 32;

    if (tid < 32) {
        int kk_g = base + tid;
        int b = kk_g / S_, kk = kk_g % S_;
        int q = kk >> 1, cls = kk & 1;
        int i = (int)((1.0f + sqrtf(8.0f * (float)q + 1.0f)) * 0.5f);
        while (i * (i - 1) / 2 > q) --i;
        while ((i + 1) * i / 2 <= q) ++i;
        int j = q - i * (i - 1) / 2;
        s_ni[tid] = b * N_ + i; s_nj[tid] = b * N_ + j;
        int e = (b * PAIRS + i * 47 + j) * 2 + cls;
        s_wk[tid][64] = bf(edge_attr, e * 2);
        s_wk[tid][65] = (float)cls;
    }
    __syncthreads();
    for (int idx = tid; idx < 32 * 64; idx += 256) {
        int t = idx >> 6, h = idx & 63;
        int cls = (int)s_wk[t][65];
        float v = bf(W_ee, h * 3) * s_wk[t][64] + bf(W_ee, h * 3 + 1 + cls) + bf(b_ee, h);
        s_wk[t][h] = fmaxf(v, 0.f);
    }
    __syncthreads();
    int tok = tid >> 3, g = tid & 7;
    int ni = s_ni[tok], nj = s_nj[tok];
    long token = base + tok;
    float4v wkv[16];
    #pragma unroll
    for (int c = 0; c < 16; c++) wkv[c] = *(const float4v*)&s_wk[tok][c * 4];

    for (int ph = 0; ph < 2; ph++) {
        for (int idx = tid; idx < 96 * 64; idx += 256) {
            int al = idx >> 6, h = idx & 63;
            int a = ph * 96 + al;
            bf16 wq = __float2bfloat16(Wq_eff[a * D_ + 64 + h]);
            bf16 wk = __float2bfloat16(Wk_eff[a * D_ + 64 + h]);
            unsigned short uq = *reinterpret_cast<unsigned short*>(&wq);
            unsigned short uk = *reinterpret_cast<unsigned short*>(&wk);
            unsigned int pr = (unsigned int)uq | ((unsigned int)uk << 16);
            *reinterpret_cast<unsigned int*>(&s_w2[al * 136 + 2 * h]) = pr;
        }
        __syncthreads();
        #pragma unroll 4
        for (int am = 0; am < 12; am++) {
            int al = g + 8 * am;
            int a = ph * 96 + al;
            float mq = 0.f, mk = 0.f;
            const unsigned short* wrow = &s_w2[al * 136];
            #pragma unroll
            for (int c = 0; c < 16; c++) {
                ushort8 w8 = *(const ushort8*)(wrow + c * 8);
                float4v w4 = wkv[c];
                mq += u2f(w8[0]) * w4.x + u2f(w8[2]) * w4.y + u2f(w8[4]) * w4.z + u2f(w8[6]) * w4.w;
                mk += u2f(w8[1]) * w4.x + u2f(w8[3]) * w4.y + u2f(w8[5]) * w4.z + u2f(w8[7]) * w4.w;
            }
            float qv = (Tq1[ni * D_ + a] + Tq3[nj * D_ + a] + mq) * QSCALE;
            float kv = Tk1[ni * D_ + a] + Tk3[nj * D_ + a] + mk;
            Q[token * D_ + a] = __float2bfloat16(qv);
            K[token * D_ + a] = __float2bfloat16(kv);
        }
        __syncthreads();
    }
    if (tid < 32) {
        float v = V13[s_ni[tid]] + V13[NODES + s_nj[tid]];
        for (int h = 0; h < 64; h++) v += wvl[64 + h] * s_wk[tid][h];
        vl[base + tid] = v;
    }
}

// ---------------- K7: split-K MFMA flash attention, NO running max -> (l,a) ---------
__device__ __forceinline__ void stage_k(const bf16* K, const float* vl, int b, int it,
                                        short* sk, float* svl, int tid) {
    #pragma unroll
    for (int r = 0; r < 3; r++) {
        int c = tid + r * 256;            // 768 chunks of 16B
        int row = c / 24, cc = c % 24;
        int key = it * 32 + row;
        int gk = b * S_ + (key < S_ ? key : S_ - 1);
        const uint4* src = (const uint4*)((const short*)K + (long)gk * D_ + cc * 8);
        *(uint4*)&sk[row * 200 + cc * 8] = *src;
    }
    if (tid < 32) {
        int key = it * 32 + tid;
        svl[tid] = (key < S_) ? vl[b * S_ + key] : 0.f;
    }
}

__global__ __launch_bounds__(256) void attn_kernel(const bf16* Q, const bf16* K,
                                                   const float* vl, float* part) {
    // 2304 blocks = 8 XCD-groups x (2 batches x 8 chunks x 18 q-groups)
    int x = blockIdx.x;
    int rr = x & 7, rest = x >> 3;       // rest 0..287
    int hi = rest >= 144;
    int b = rr + 8 * hi;
    int s = rest - 144 * hi;             // 0..143
    int chunk = s / 18, qg = s % 18;
    int tid = threadIdx.x;
    int wave = tid >> 6, lane = tid & 63;
    int n5 = lane & 31, h5 = lane >> 5;
    int qt = qg * 4 + wave;              // 0..71 (71 invalid)
    bool qvalid = qt < QTILES;
    int t0 = chunk * 9;
    int nit = (chunk == 7) ? 8 : 9;      // chunk 7: iters 63..70 (last is ragged)

    __shared__ short s_k[2][32 * 200];
    __shared__ float s_vl[2][32];

    short8 qf[12];
    {
        int qrow = b * S_ + qt * 32 + n5;
        if (qrow > B_ * S_ - 1) qrow = B_ * S_ - 1;
        const short* qp = (const short*)Q + (long)qrow * D_;
        #pragma unroll
        for (int kc = 0; kc < 12; kc++) qf[kc] = *(const short8*)(qp + kc * 16 + h5 * 8);
    }

    float lr[16], ar[16];
    #pragma unroll
    for (int r = 0; r < 16; r++) { lr[r] = 0.f; ar[r] = 0.f; }

    stage_k(K, vl, b, t0, s_k[0], s_vl[0], tid);

    for (int k = 0; k < nit; ++k) {
        int it = t0 + k;
        int buf = k & 1;
        __syncthreads();
        if (k + 1 < nit)
            stage_k(K, vl, b, it + 1, s_k[buf ^ 1], s_vl[buf ^ 1], tid);
        const short* kb = s_k[buf];
        float16v c;
        #pragma unroll
        for (int r = 0; r < 16; r++) c[r] = 0.f;
        #pragma unroll
        for (int kc = 0; kc < 12; kc++) {
            short8 bfr = *(const short8*)(kb + n5 * 200 + kc * 16 + h5 * 8);
            c = __builtin_amdgcn_mfma_f32_32x32x16_bf16(qf[kc], bfr, c, 0, 0, 0);
        }
        float vlv = s_vl[buf][n5];
        if (it != KITERS - 1) {          // full tile: no masking, 3 VALU/row
            #pragma unroll
            for (int r = 0; r < 16; r++) {
                float p = __builtin_amdgcn_exp2f(c[r]);   // scores in log2 domain
                lr[r] += p;
                ar[r] += p * vlv;
            }
        } else {                         // ragged last tile: keys >= S_ masked
            bool kv = n5 < 16;           // keys 2240..2255 valid, 2256..2271 not
            #pragma unroll
            for (int r = 0; r < 16; r++) {
                float p = kv ? __builtin_amdgcn_exp2f(c[r]) : 0.f;
                lr[r] += p;
                ar[r] += p * vlv;
            }
        }
    }

    if (qvalid) {
        #pragma unroll
        for (int r = 0; r < 16; r++) {
            float l = lr[r], a = ar[r];
            #pragma unroll
            for (int off = 1; off < 32; off <<= 1) {
                l += __shfl_xor(l, off, 64);
                a += __shfl_xor(a, off, 64);
            }
            if (n5 == 0) {
                int qrow = qt * 32 + (r & 3) + 8 * (r >> 2) + 4 * h5;
                if (qrow < S_) {
                    float2v pv = {l, a};
                    *(float2v*)&part[((long)(b * S_ + qrow) * 8 + chunk) * 2] = pv;
                }
            }
        }
    }
}

// ---------------- K8: merge partials (plain sums) + pairing/argmin ----------------
__global__ __launch_bounds__(256) void final_kernel(const float* part, const float* sc,
                                                    float* out) {
    int idx = blockIdx.x * 256 + threadIdx.x;
    if (idx >= B_ * SH) return;
    int b = idx / SH, p = idx % SH;
    int i = (int)((1.0f + sqrtf(8.0f * (float)p + 1.0f)) * 0.5f);
    while (i * (i - 1) / 2 > p) --i;
    while ((i + 1) * i / 2 <= p) ++i;
    int j = p - i * (i - 1) / 2;
    float co = sc[1];
    float lg[2];
    #pragma unroll
    for (int t = 0; t < 2; t++) {
        long g = (long)b * S_ + 2 * p + t;
        float l = 0.f, a = 0.f;
        #pragma unroll
        for (int c = 0; c < 8; c++) {
            float2v pc = *(const float2v*)&part[(g * 8 + c) * 2];
            l += pc.x;
            a += pc.y;
        }
        lg[t] = sanitize(a / l + co);
    }
    int ind = (lg[1] < lg[0]) ? 1 : 0;
    float ef = ind ? lg[1] : lg[0];
    out[(b * SH + p) * 2 + 0] = (float)(b * N_ + i);
    out[(b * SH + p) * 2 + 1] = (float)(b * N_ + j);
    out[2 * B_ * SH + idx] = ef;
    out[2 * B_ * SH + B_ * SH + idx] = (float)ind;
}

extern "C" void kernel_launch(void* const* d_in, const int* in_sizes, int n_in,
                              void* d_out, int out_size, void* d_ws, size_t ws_size,
                              hipStream_t stream) {
    const bf16* x         = (const bf16*)d_in[0];
    const bf16* edge_attr = (const bf16*)d_in[2];
    const bf16* W_we   = (const bf16*)d_in[5];
    const bf16* b_we   = (const bf16*)d_in[6];
    const bf16* Wrel1  = (const bf16*)d_in[7];
    const bf16* brel1  = (const bf16*)d_in[8];
    const bf16* Wroot1 = (const bf16*)d_in[9];
    const bf16* Wrel2  = (const bf16*)d_in[10];
    const bf16* brel2  = (const bf16*)d_in[11];
    const bf16* Wroot2 = (const bf16*)d_in[12];
    const bf16* W_ee   = (const bf16*)d_in[13];
    const bf16* b_ee   = (const bf16*)d_in[14];
    const bf16* W_qkv  = (const bf16*)d_in[15];
    const bf16* b_qkv  = (const bf16*)d_in[16];
    const bf16* W_in   = (const bf16*)d_in[17];
    const bf16* b_in   = (const bf16*)d_in[18];
    const bf16* W_out  = (const bf16*)d_in[19];
    const bf16* b_out  = (const bf16*)d_in[20];
    const bf16* W_o    = (const bf16*)d_in[21];
    const bf16* b_o    = (const bf16*)d_in[22];

    float* w = (float*)d_ws;
    float* Wq_eff = w;                  // 36864
    float* Wk_eff = Wq_eff + 36864;     // 36864
    float* wvl    = Wk_eff + 36864;     // 192
    float* bq_eff = wvl + 192;
    float* bk_eff = bq_eff + 192;
    float* bv_eff = bk_eff + 192;
    float* wo_eff = bv_eff + 192;
    float* t_m    = wo_eff + 192;
    float* sc     = t_m + 192;          // 64 (2 used)
    float* x2     = sc + 64;            // 49152
    float* vl     = x2 + 49152;         // 36096
    float* part   = vl + 36096;         // 36096*8*2 = 577536
    bf16*  Q      = (bf16*)(part + 577536);   // EK*192 bf16
    bf16*  K      = Q + (long)EK * D_;        // EK*192 bf16
    float* Tq1    = (float*)(K + (long)EK * D_);
    float* Tq3    = Tq1 + NODES * D_;
    float* Tk1    = Tq3 + NODES * D_;
    float* Tk3    = Tk1 + NODES * D_;
    float* V13    = Tk3 + NODES * D_;   // 1536
    // total ~36 MB of 256 MB workspace

    graphconv_kernel<<<B_, 256, 0, stream>>>(edge_attr, W_we, b_we, x, Wrel1, brel1, Wroot1,
                                             Wrel2, brel2, Wroot2, x2);
    compose_a1<<<193, 256, 0, stream>>>(W_o, b_o, W_out, b_out, W_in, b_in, b_qkv,
                                        wo_eff, bq_eff, bk_eff, bv_eff, sc);
    compose_a2<<<49, 256, 0, stream>>>(W_in, wo_eff, bv_eff, t_m, sc);
    compose_b<<<(2 * D_ * D_ + D_ + 255) / 256, 256, 0, stream>>>(W_in, W_qkv, t_m, Wq_eff,
                                                                  Wk_eff, wvl);
    nodeproj_kernel<<<NODES, 256, 0, stream>>>(x2, Wq_eff, Wk_eff, wvl, bq_eff, bk_eff, sc,
                                               Tq1, Tq3, Tk1, Tk3, V13);
    qkvmid_kernel<<<EK / 32, 256, 0, stream>>>(edge_attr, W_ee, b_ee, Wq_eff, Wk_eff, wvl,
                                               Tq1, Tq3, Tk1, Tk3, V13, Q, K, vl);
    attn_kernel<<<2304, 256, 0, stream>>>(Q, K, vl, part);
    final_kernel<<<(B_ * SH + 255) / 256, 256, 0, stream>>>(part, sc, (float*)d_out);
}

// Round 10
// 299.770 us; speedup vs baseline: 12.1803x; 1.0887x over previous
//
#include <hip/hip_runtime.h>
#include <hip/hip_bf16.h>

typedef __hip_bfloat16 bf16;
typedef __attribute__((ext_vector_type(8))) short short8;
typedef __attribute__((ext_vector_type(16))) float float16v;
typedef __attribute__((ext_vector_type(2))) float float2v;

#define B_     16
#define N_     48
#define NODES  768
#define PAIRS  2256
#define EK     36096
#define S_     2256
#define SH     1128
#define D_     192
#define KITERS 71
#define QTILES 71
#define QSCALE 0.10411754f  // log2(e)/sqrt(192): folded into Q at store

__device__ __forceinline__ float bf(const bf16* p, int i) { return __bfloat162float(p[i]); }
__device__ __forceinline__ float u2f(unsigned short u) {
    return __uint_as_float(((unsigned int)u) << 16);
}
__device__ __forceinline__ float sanitize(float v) {
    if (v > -1e4f && v < 1e4f) return v;
    if (v >= 1e4f) return 1e4f;
    if (v <= -1e4f) return -1e4f;
    return 0.f;  // NaN
}

// ---------------- K1: fused edge-weight + 2-layer GraphConv, one block/batch ----------
__global__ __launch_bounds__(256) void graphconv_kernel(
    const bf16* edge_attr, const bf16* W_we, const bf16* b_we, const bf16* x,
    const bf16* Wrel1, const bf16* brel1, const bf16* Wroot1,
    const bf16* Wrel2, const bf16* brel2, const bf16* Wroot2, float* x2out) {
    int b = blockIdx.x, tid = threadIdx.x;
    __shared__ float s_ws[N_ * N_];
    __shared__ float s_x[N_ * 5], s_agg1[N_ * 5];
    __shared__ float s_x1[N_ * 32], s_agg2[N_ * 32];
    float we0 = bf(W_we, 0), we1 = bf(W_we, 1), we2 = bf(W_we, 2), bw = bf(b_we, 0);
    for (int idx = tid; idx < N_ * N_; idx += 256) {
        int i = idx / N_, j = idx % N_;
        float v = 0.f;
        if (i != j) {
            int p = i * 47 + (j < i ? j : j - 1);
            int e = (b * PAIRS + p) * 2;
            float w0 = fmaxf(we0 * bf(edge_attr, (e + 0) * 2) + we1 + bw, 0.f);
            float w1 = fmaxf(we0 * bf(edge_attr, (e + 1) * 2) + we2 + bw, 0.f);
            v = w0 + w1;
        }
        s_ws[idx] = v;
    }
    for (int idx = tid; idx < N_ * 5; idx += 256) s_x[idx] = bf(x, b * N_ * 5 + idx);
    __syncthreads();
    if (tid < 240) {
        int j = tid / 5, f = tid % 5;
        float a = 0.f;
        for (int i = 0; i < N_; i++) a += s_ws[i * N_ + j] * s_x[i * 5 + f];
        s_agg1[tid] = a;
    }
    __syncthreads();
    for (int o = tid; o < N_ * 32; o += 256) {
        int j = o >> 5, h = o & 31;
        float a = bf(brel1, h);
        for (int f = 0; f < 5; f++)
            a += bf(Wrel1, h * 5 + f) * s_agg1[j * 5 + f] + bf(Wroot1, h * 5 + f) * s_x[j * 5 + f];
        s_x1[o] = fmaxf(a, 0.f);
    }
    __syncthreads();
    for (int o = tid; o < N_ * 32; o += 256) {
        int j = o >> 5, h = o & 31;
        float a = 0.f;
        for (int i = 0; i < N_; i++) a += s_ws[i * N_ + j] * s_x1[i * 32 + h];
        s_agg2[o] = a;
    }
    __syncthreads();
    for (int o = tid; o < N_ * 64; o += 256) {
        int j = o >> 6, h2 = o & 63;
        float a = bf(brel2, h2);
        for (int h1 = 0; h1 < 32; h1++)
            a += bf(Wrel2, h2 * 32 + h1) * s_agg2[j * 32 + h1] +
                 bf(Wroot2, h2 * 32 + h1) * s_x1[j * 32 + h1];
        x2out[(b * N_ + j) * 64 + h2] = fmaxf(a, 0.f);
    }
}

// ---------------- K2: compose stage A1 — wave-parallel dot products ----------------
__global__ __launch_bounds__(256) void compose_a1(
    const bf16* W_o, const bf16* b_o, const bf16* W_out, const bf16* b_out,
    const bf16* W_in, const bf16* b_in, const bf16* b_qkv,
    float* wo_eff, float* bq_eff, float* bk_eff, float* bv_eff, float* sc) {
    int a = blockIdx.x;  // 0..191 outputs; block 192 = co
    int wave = threadIdx.x >> 6, lane = threadIdx.x & 63;
    float partial = 0.f;
    if (a < 192) {
        if (wave == 0) {
            for (int m = lane; m < 192; m += 64) partial += bf(W_o, m) * bf(W_out, m * 192 + a);
        } else {
            int row = (wave - 1) * 192 + a;
            for (int m = lane; m < 192; m += 64)
                partial += bf(W_in, row * 192 + m) * bf(b_qkv, (wave - 1) * 192 + m);
        }
    } else if (wave == 0) {
        for (int m = lane; m < 192; m += 64) partial += bf(W_o, m) * bf(b_out, m);
    }
    for (int off = 32; off; off >>= 1) partial += __shfl_xor(partial, off, 64);
    if (lane == 0) {
        if (a < 192) {
            if (wave == 0) wo_eff[a] = partial;
            else if (wave == 1) bq_eff[a] = partial + bf(b_in, a);
            else if (wave == 2) bk_eff[a] = partial + bf(b_in, 192 + a);
            else bv_eff[a] = partial + bf(b_in, 384 + a);
        } else if (wave == 0) sc[1] = partial + bf(b_o, 0);
    }
}

// ---------------- K3: compose stage A2 — t_m (needs wo_eff), bvl ----------------
__global__ __launch_bounds__(256) void compose_a2(const bf16* W_in, const float* wo_eff,
                                                  const float* bv_eff, float* t_m, float* sc) {
    int w = blockIdx.x * 4 + (threadIdx.x >> 6);
    int lane = threadIdx.x & 63;
    float partial = 0.f;
    if (w < 192) {
        for (int aa = lane; aa < 192; aa += 64)
            partial += wo_eff[aa] * bf(W_in, (384 + aa) * 192 + w);
    } else if (w == 192) {
        for (int aa = lane; aa < 192; aa += 64) partial += wo_eff[aa] * bv_eff[aa];
    }
    for (int off = 32; off; off >>= 1) partial += __shfl_xor(partial, off, 64);
    if (lane == 0) {
        if (w < 192) t_m[w] = partial;
        else if (w == 192) sc[0] = partial;
    }
}

// ---------------- K4: compose stage B (matrices) + bf16 W2 tables ----------------
__global__ __launch_bounds__(256) void compose_b(const bf16* W_in, const bf16* W_qkv,
                                                 const float* t_m, float* Wq_eff,
                                                 float* Wk_eff, float* wvl, bf16* W2b) {
    int idx = blockIdx.x * 256 + threadIdx.x;
    if (idx < D_ * D_) {
        int a = idx / D_, c = idx % D_;
        float acc = 0.f;
        for (int m = 0; m < D_; m++) acc += bf(W_in, a * D_ + m) * bf(W_qkv, m * D_ + c);
        Wq_eff[idx] = acc;
        if (c >= 64 && c < 128) W2b[a * 64 + (c - 64)] = __float2bfloat16(acc);
    } else if (idx < 2 * D_ * D_) {
        int t = idx - D_ * D_, a = t / D_, c = t % D_;
        float acc = 0.f;
        for (int m = 0; m < D_; m++)
            acc += bf(W_in, (D_ + a) * D_ + m) * bf(W_qkv, (D_ + m) * D_ + c);
        Wk_eff[t] = acc;
        if (c >= 64 && c < 128) W2b[(192 + a) * 64 + (c - 64)] = __float2bfloat16(acc);
    } else if (idx < 2 * D_ * D_ + D_) {
        int c = idx - 2 * D_ * D_;
        float acc = 0.f;
        for (int m = 0; m < D_; m++) acc += t_m[m] * bf(W_qkv, (2 * D_ + m) * D_ + c);
        wvl[c] = acc;
    }
}

// ---------------- K5: per-node projections ----------------
__global__ __launch_bounds__(256) void nodeproj_kernel(
    const float* x2, const float* Wq_eff, const float* Wk_eff, const float* wvl,
    const float* bq_eff, const float* bk_eff, const float* sc,
    float* Tq1, float* Tq3, float* Tk1, float* Tk3, float* V13) {
    int n = blockIdx.x;
    __shared__ float sx[64];
    int tid = threadIdx.x;
    if (tid < 64) sx[tid] = x2[n * 64 + tid];
    __syncthreads();
    if (tid < D_) {
        int a = tid;
        float q1 = bq_eff[a], q3 = 0.f, k1 = bk_eff[a], k3 = 0.f;
        const float* wq = Wq_eff + a * D_;
        const float* wk = Wk_eff + a * D_;
        for (int c = 0; c < 64; c++) {
            float xv = sx[c];
            q1 += wq[c] * xv;       q3 += wq[128 + c] * xv;
            k1 += wk[c] * xv;       k3 += wk[128 + c] * xv;
        }
        Tq1[n * D_ + a] = q1; Tq3[n * D_ + a] = q3;
        Tk1[n * D_ + a] = k1; Tk3[n * D_ + a] = k3;
    } else if (tid == 192 || tid == 193) {
        int part = tid - 192;
        float v = (part == 0) ? sc[0] : 0.f;
        for (int c = 0; c < 64; c++) v += wvl[part * 128 + c] * sx[c];
        V13[part * NODES + n] = v;
    }
}

// ---------------- K6: MFMA per-edge mid-GEMM + T-combine -> Q,K,vl ----------------
__global__ __launch_bounds__(256) void qkvmid_kernel(
    const bf16* edge_attr, const bf16* W_ee, const bf16* b_ee, const bf16* W2b,
    const float* wvl,
    const float* Tq1, const float* Tq3, const float* Tk1, const float* Tk3,
    const float* V13, bf16* Q, bf16* K, float* vl) {
    __shared__ short s_w2[384 * 72];   // W2 q rows 0..191, k rows 192..383 (144B stride)
    __shared__ short s_wk[32 * 72];    // wK bf16, MFMA-A layout
    __shared__ int s_ni[32], s_nj[32];
    __shared__ float s_wraw[32], s_cls[32];
    int tid = threadIdx.x, base = blockIdx.x * 32;

    for (int c = tid; c < 3072; c += 256) {          // stage W2b (49 KB) -> LDS
        int row = c >> 3, off = c & 7;
        uint4 v = *(const uint4*)((const short*)W2b + row * 64 + off * 8);
        *(uint4*)&s_w2[row * 72 + off * 8] = v;
    }
    if (tid < 32) {                                   // token meta
        int kk_g = base + tid;
        int b = kk_g / S_, kk = kk_g % S_;
        int q = kk >> 1, cls = kk & 1;
        int i = (int)((1.0f + sqrtf(8.0f * (float)q + 1.0f)) * 0.5f);
        while (i * (i - 1) / 2 > q) --i;
        while ((i + 1) * i / 2 <= q) ++i;
        int j = q - i * (i - 1) / 2;
        s_ni[tid] = b * N_ + i; s_nj[tid] = b * N_ + j;
        int e = (b * PAIRS + i * 47 + j) * 2 + cls;
        s_wraw[tid] = bf(edge_attr, e * 2);
        s_cls[tid] = (float)cls;
    }
    __syncthreads();
    for (int idx = tid; idx < 32 * 64; idx += 256) {  // wK = relu(edge emb), bf16
        int t = idx >> 6, h = idx & 63;
        int cls = (int)s_cls[t];
        float v = bf(W_ee, h * 3) * s_wraw[t] + bf(W_ee, h * 3 + 1 + cls) + bf(b_ee, h);
        bf16 bv = __float2bfloat16(fmaxf(v, 0.f));
        s_wk[t * 72 + h] = *reinterpret_cast<short*>(&bv);
    }
    __syncthreads();

    int wave = tid >> 6, lane = tid & 63;
    int l5 = lane & 31, h5 = lane >> 5;

    short8 af[4];                                     // A-frags: wK rows
    #pragma unroll
    for (int kc = 0; kc < 4; kc++)
        af[kc] = *(const short8*)&s_wk[l5 * 72 + kc * 16 + h5 * 8];

    int tl[16], niv[16], njv[16];                     // epilogue token indices
    #pragma unroll
    for (int r = 0; r < 16; r++) {
        int t = (r & 3) + 8 * (r >> 2) + 4 * h5;
        tl[r] = t; niv[r] = s_ni[t]; njv[r] = s_nj[t];
    }

    #pragma unroll
    for (int tt = 0; tt < 3; tt++) {                  // 12 tiles / 4 waves
        int ta = wave + tt * 4;                       // 0..11
        bool isq = ta < 6;
        int ag = (isq ? ta : ta - 6) * 32 + l5;       // output index a
        float16v c;
        #pragma unroll
        for (int r = 0; r < 16; r++) c[r] = 0.f;
        #pragma unroll
        for (int kc = 0; kc < 4; kc++) {
            short8 bfr = *(const short8*)&s_w2[(ta * 32 + l5) * 72 + kc * 16 + h5 * 8];
            c = __builtin_amdgcn_mfma_f32_32x32x16_bf16(af[kc], bfr, c, 0, 0, 0);
        }
        const float* T1 = isq ? Tq1 : Tk1;
        const float* T3 = isq ? Tq3 : Tk3;
        bf16* Out = isq ? Q : K;
        #pragma unroll
        for (int r = 0; r < 16; r++) {
            float v = c[r] + T1[niv[r] * D_ + ag] + T3[njv[r] * D_ + ag];
            if (isq) v *= QSCALE;
            Out[(long)(base + tl[r]) * D_ + ag] = __float2bfloat16(v);
        }
    }
    if (tid < 32) {                                   // vl
        float v = V13[s_ni[tid]] + V13[NODES + s_nj[tid]];
        for (int h = 0; h < 64; h++)
            v += wvl[64 + h] * u2f((unsigned short)s_wk[tid * 72 + h]);
        vl[base + tid] = v;
    }
}

// ---------------- K7: split-K MFMA flash attention, NO running max -> (l,a) ---------
__device__ __forceinline__ void stage_k(const bf16* K, const float* vl, int b, int it,
                                        short* sk, float* svl, int tid) {
    #pragma unroll
    for (int r = 0; r < 3; r++) {
        int c = tid + r * 256;            // 768 chunks of 16B
        int row = c / 24, cc = c % 24;
        int key = it * 32 + row;
        int gk = b * S_ + (key < S_ ? key : S_ - 1);
        const uint4* src = (const uint4*)((const short*)K + (long)gk * D_ + cc * 8);
        *(uint4*)&sk[row * 200 + cc * 8] = *src;
    }
    if (tid < 32) {
        int key = it * 32 + tid;
        svl[tid] = (key < S_) ? vl[b * S_ + key] : 0.f;
    }
}

__global__ __launch_bounds__(256) void attn_kernel(const bf16* Q, const bf16* K,
                                                   const float* vl, float* part) {
    int x = blockIdx.x;
    int rr = x & 7, rest = x >> 3;       // rest 0..287
    int hi = rest >= 144;
    int b = rr + 8 * hi;
    int s = rest - 144 * hi;             // 0..143
    int chunk = s / 18, qg = s % 18;
    int tid = threadIdx.x;
    int wave = tid >> 6, lane = tid & 63;
    int n5 = lane & 31, h5 = lane >> 5;
    int qt = qg * 4 + wave;              // 0..71 (71 invalid)
    bool qvalid = qt < QTILES;
    int t0 = chunk * 9;
    int nit = (chunk == 7) ? 8 : 9;

    __shared__ short s_k[2][32 * 200];
    __shared__ float s_vl[2][32];

    short8 qf[12];
    {
        int qrow = b * S_ + qt * 32 + n5;
        if (qrow > B_ * S_ - 1) qrow = B_ * S_ - 1;
        const short* qp = (const short*)Q + (long)qrow * D_;
        #pragma unroll
        for (int kc = 0; kc < 12; kc++) qf[kc] = *(const short8*)(qp + kc * 16 + h5 * 8);
    }

    float lr[16], ar[16];
    #pragma unroll
    for (int r = 0; r < 16; r++) { lr[r] = 0.f; ar[r] = 0.f; }

    stage_k(K, vl, b, t0, s_k[0], s_vl[0], tid);

    for (int k = 0; k < nit; ++k) {
        int it = t0 + k;
        int buf = k & 1;
        __syncthreads();
        if (k + 1 < nit)
            stage_k(K, vl, b, it + 1, s_k[buf ^ 1], s_vl[buf ^ 1], tid);
        const short* kb = s_k[buf];
        float16v c;
        #pragma unroll
        for (int r = 0; r < 16; r++) c[r] = 0.f;
        #pragma unroll
        for (int kc = 0; kc < 12; kc++) {
            short8 bfr = *(const short8*)(kb + n5 * 200 + kc * 16 + h5 * 8);
            c = __builtin_amdgcn_mfma_f32_32x32x16_bf16(qf[kc], bfr, c, 0, 0, 0);
        }
        float vlv = s_vl[buf][n5];
        if (it != KITERS - 1) {
            #pragma unroll
            for (int r = 0; r < 16; r++) {
                float p = __builtin_amdgcn_exp2f(c[r]);
                lr[r] += p;
                ar[r] += p * vlv;
            }
        } else {
            bool kv = n5 < 16;
            #pragma unroll
            for (int r = 0; r < 16; r++) {
                float p = kv ? __builtin_amdgcn_exp2f(c[r]) : 0.f;
                lr[r] += p;
                ar[r] += p * vlv;
            }
        }
    }

    if (qvalid) {
        #pragma unroll
        for (int r = 0; r < 16; r++) {
            float l = lr[r], a = ar[r];
            #pragma unroll
            for (int off = 1; off < 32; off <<= 1) {
                l += __shfl_xor(l, off, 64);
                a += __shfl_xor(a, off, 64);
            }
            if (n5 == 0) {
                int qrow = qt * 32 + (r & 3) + 8 * (r >> 2) + 4 * h5;
                if (qrow < S_) {
                    float2v pv = {l, a};
                    *(float2v*)&part[((long)(b * S_ + qrow) * 8 + chunk) * 2] = pv;
                }
            }
        }
    }
}

// ---------------- K8: merge partials (plain sums) + pairing/argmin ----------------
__global__ __launch_bounds__(256) void final_kernel(const float* part, const float* sc,
                                                    float* out) {
    int idx = blockIdx.x * 256 + threadIdx.x;
    if (idx >= B_ * SH) return;
    int b = idx / SH, p = idx % SH;
    int i = (int)((1.0f + sqrtf(8.0f * (float)p + 1.0f)) * 0.5f);
    while (i * (i - 1) / 2 > p) --i;
    while ((i + 1) * i / 2 <= p) ++i;
    int j = p - i * (i - 1) / 2;
    float co = sc[1];
    float lg[2];
    #pragma unroll
    for (int t = 0; t < 2; t++) {
        long g = (long)b * S_ + 2 * p + t;
        float l = 0.f, a = 0.f;
        #pragma unroll
        for (int c = 0; c < 8; c++) {
            float2v pc = *(const float2v*)&part[(g * 8 + c) * 2];
            l += pc.x;
            a += pc.y;
        }
        lg[t] = sanitize(a / l + co);
    }
    int ind = (lg[1] < lg[0]) ? 1 : 0;
    float ef = ind ? lg[1] : lg[0];
    out[(b * SH + p) * 2 + 0] = (float)(b * N_ + i);
    out[(b * SH + p) * 2 + 1] = (float)(b * N_ + j);
    out[2 * B_ * SH + idx] = ef;
    out[2 * B_ * SH + B_ * SH + idx] = (float)ind;
}

extern "C" void kernel_launch(void* const* d_in, const int* in_sizes, int n_in,
                              void* d_out, int out_size, void* d_ws, size_t ws_size,
                              hipStream_t stream) {
    const bf16* x         = (const bf16*)d_in[0];
    const bf16* edge_attr = (const bf16*)d_in[2];
    const bf16* W_we   = (const bf16*)d_in[5];
    const bf16* b_we   = (const bf16*)d_in[6];
    const bf16* Wrel1  = (const bf16*)d_in[7];
    const bf16* brel1  = (const bf16*)d_in[8];
    const bf16* Wroot1 = (const bf16*)d_in[9];
    const bf16* Wrel2  = (const bf16*)d_in[10];
    const bf16* brel2  = (const bf16*)d_in[11];
    const bf16* Wroot2 = (const bf16*)d_in[12];
    const bf16* W_ee   = (const bf16*)d_in[13];
    const bf16* b_ee   = (const bf16*)d_in[14];
    const bf16* W_qkv  = (const bf16*)d_in[15];
    const bf16* b_qkv  = (const bf16*)d_in[16];
    const bf16* W_in   = (const bf16*)d_in[17];
    const bf16* b_in   = (const bf16*)d_in[18];
    const bf16* W_out  = (const bf16*)d_in[19];
    const bf16* b_out  = (const bf16*)d_in[20];
    const bf16* W_o    = (const bf16*)d_in[21];
    const bf16* b_o    = (const bf16*)d_in[22];

    float* w = (float*)d_ws;
    float* Wq_eff = w;                  // 36864
    float* Wk_eff = Wq_eff + 36864;     // 36864
    float* wvl    = Wk_eff + 36864;     // 192
    float* bq_eff = wvl + 192;
    float* bk_eff = bq_eff + 192;
    float* bv_eff = bk_eff + 192;
    float* wo_eff = bv_eff + 192;
    float* t_m    = wo_eff + 192;
    float* sc     = t_m + 192;          // 64 (2 used)
    float* x2     = sc + 64;            // 49152
    float* vl     = x2 + 49152;         // 36096
    float* part   = vl + 36096;         // 577536
    bf16*  Q      = (bf16*)(part + 577536);   // EK*192 bf16
    bf16*  K      = Q + (long)EK * D_;        // EK*192 bf16
    bf16*  W2b    = K + (long)EK * D_;        // 384*64 bf16
    float* Tq1    = (float*)(W2b + 384 * 64);
    float* Tq3    = Tq1 + NODES * D_;
    float* Tk1    = Tq3 + NODES * D_;
    float* Tk3    = Tk1 + NODES * D_;
    float* V13    = Tk3 + NODES * D_;   // 1536
    // total ~36 MB of 256 MB workspace

    graphconv_kernel<<<B_, 256, 0, stream>>>(edge_attr, W_we, b_we, x, Wrel1, brel1, Wroot1,
                                             Wrel2, brel2, Wroot2, x2);
    compose_a1<<<193, 256, 0, stream>>>(W_o, b_o, W_out, b_out, W_in, b_in, b_qkv,
                                        wo_eff, bq_eff, bk_eff, bv_eff, sc);
    compose_a2<<<49, 256, 0, stream>>>(W_in, wo_eff, bv_eff, t_m, sc);
    compose_b<<<(2 * D_ * D_ + D_ + 255) / 256, 256, 0, stream>>>(W_in, W_qkv, t_m, Wq_eff,
                                                                  Wk_eff, wvl, W2b);
    nodeproj_kernel<<<NODES, 256, 0, stream>>>(x2, Wq_eff, Wk_eff, wvl, bq_eff, bk_eff, sc,
                                               Tq1, Tq3, Tk1, Tk3, V13);
    qkvmid_kernel<<<EK / 32, 256, 0, stream>>>(edge_attr, W_ee, b_ee, W2b, wvl,
                                               Tq1, Tq3, Tk1, Tk3, V13, Q, K, vl);
    attn_kernel<<<2304, 256, 0, stream>>>(Q, K, vl, part);
    final_kernel<<<(B_ * SH + 255) / 256, 256, 0, stream>>>(part, sc, (float*)d_out);
}

// Round 11
// 273.460 us; speedup vs baseline: 13.3522x; 1.0962x over previous
//
#include <hip/hip_runtime.h>
#include <hip/hip_bf16.h>

typedef __hip_bfloat16 bf16;
typedef __attribute__((ext_vector_type(8))) short short8;
typedef __attribute__((ext_vector_type(16))) float float16v;
typedef __attribute__((ext_vector_type(2))) float float2v;

#define B_     16
#define N_     48
#define NODES  768
#define PAIRS  2256
#define EK     36096
#define S_     2256
#define SH     1128
#define D_     192
#define KITERS 71
#define QTILES 71
#define QSCALE 0.10411754f  // log2(e)/sqrt(192): folded into Q at store

__device__ __forceinline__ float bf(const bf16* p, int i) { return __bfloat162float(p[i]); }
__device__ __forceinline__ float u2f(unsigned short u) {
    return __uint_as_float(((unsigned int)u) << 16);
}
__device__ __forceinline__ float sanitize(float v) {
    if (v > -1e4f && v < 1e4f) return v;
    if (v >= 1e4f) return 1e4f;
    if (v <= -1e4f) return -1e4f;
    return 0.f;  // NaN
}

// ============ STAGE 1: graphconv (blocks 0..15) | compose_a1 (16..208) |
// ============          compose_b (209..496)  — mutually independent ============
__global__ __launch_bounds__(256) void stage1_kernel(
    const bf16* edge_attr, const bf16* W_we, const bf16* b_we, const bf16* x,
    const bf16* Wrel1, const bf16* brel1, const bf16* Wroot1,
    const bf16* Wrel2, const bf16* brel2, const bf16* Wroot2,
    const bf16* W_o, const bf16* b_o, const bf16* W_out, const bf16* b_out,
    const bf16* W_in, const bf16* b_in, const bf16* b_qkv, const bf16* W_qkv,
    float* x2out, float* wo_eff, float* bq_eff, float* bk_eff, float* bv_eff, float* sc,
    float* WqT, float* WkT, bf16* W2b) {
    int blk = blockIdx.x, tid = threadIdx.x;
    if (blk < 16) {  // ---- graphconv, one block per batch ----
        int b = blk;
        __shared__ float s_ws[N_ * N_];
        __shared__ float s_x[N_ * 5], s_agg1[N_ * 5];
        __shared__ float s_x1[N_ * 32], s_agg2[N_ * 32];
        float we0 = bf(W_we, 0), we1 = bf(W_we, 1), we2 = bf(W_we, 2), bw = bf(b_we, 0);
        for (int idx = tid; idx < N_ * N_; idx += 256) {
            int i = idx / N_, j = idx % N_;
            float v = 0.f;
            if (i != j) {
                int p = i * 47 + (j < i ? j : j - 1);
                int e = (b * PAIRS + p) * 2;
                float w0 = fmaxf(we0 * bf(edge_attr, (e + 0) * 2) + we1 + bw, 0.f);
                float w1 = fmaxf(we0 * bf(edge_attr, (e + 1) * 2) + we2 + bw, 0.f);
                v = w0 + w1;
            }
            s_ws[idx] = v;
        }
        for (int idx = tid; idx < N_ * 5; idx += 256) s_x[idx] = bf(x, b * N_ * 5 + idx);
        __syncthreads();
        if (tid < 240) {
            int j = tid / 5, f = tid % 5;
            float a = 0.f;
            for (int i = 0; i < N_; i++) a += s_ws[i * N_ + j] * s_x[i * 5 + f];
            s_agg1[tid] = a;
        }
        __syncthreads();
        for (int o = tid; o < N_ * 32; o += 256) {
            int j = o >> 5, h = o & 31;
            float a = bf(brel1, h);
            for (int f = 0; f < 5; f++)
                a += bf(Wrel1, h * 5 + f) * s_agg1[j * 5 + f] +
                     bf(Wroot1, h * 5 + f) * s_x[j * 5 + f];
            s_x1[o] = fmaxf(a, 0.f);
        }
        __syncthreads();
        for (int o = tid; o < N_ * 32; o += 256) {
            int j = o >> 5, h = o & 31;
            float a = 0.f;
            for (int i = 0; i < N_; i++) a += s_ws[i * N_ + j] * s_x1[i * 32 + h];
            s_agg2[o] = a;
        }
        __syncthreads();
        for (int o = tid; o < N_ * 64; o += 256) {
            int j = o >> 6, h2 = o & 63;
            float a = bf(brel2, h2);
            for (int h1 = 0; h1 < 32; h1++)
                a += bf(Wrel2, h2 * 32 + h1) * s_agg2[j * 32 + h1] +
                     bf(Wroot2, h2 * 32 + h1) * s_x1[j * 32 + h1];
            x2out[(b * N_ + j) * 64 + h2] = fmaxf(a, 0.f);
        }
    } else if (blk < 209) {  // ---- compose_a1 ----
        int a = blk - 16;  // 0..191 outputs; 192 = co
        int wave = tid >> 6, lane = tid & 63;
        float partial = 0.f;
        if (a < 192) {
            if (wave == 0) {
                for (int m = lane; m < 192; m += 64)
                    partial += bf(W_o, m) * bf(W_out, m * 192 + a);
            } else {
                int row = (wave - 1) * 192 + a;
                for (int m = lane; m < 192; m += 64)
                    partial += bf(W_in, row * 192 + m) * bf(b_qkv, (wave - 1) * 192 + m);
            }
        } else if (wave == 0) {
            for (int m = lane; m < 192; m += 64) partial += bf(W_o, m) * bf(b_out, m);
        }
        for (int off = 32; off; off >>= 1) partial += __shfl_xor(partial, off, 64);
        if (lane == 0) {
            if (a < 192) {
                if (wave == 0) wo_eff[a] = partial;
                else if (wave == 1) bq_eff[a] = partial + bf(b_in, a);
                else if (wave == 2) bk_eff[a] = partial + bf(b_in, 192 + a);
                else bv_eff[a] = partial + bf(b_in, 384 + a);
            } else if (wave == 0) sc[1] = partial + bf(b_o, 0);
        }
    } else {  // ---- compose_b: Wq/Wk transposed tables + W2b bf16 ----
        int idx = (blk - 209) * 256 + tid;  // 0 .. 2*D*D-1
        if (idx < D_ * D_) {
            int a = idx / D_, c = idx % D_;
            float acc = 0.f;
            for (int m = 0; m < D_; m++) acc += bf(W_in, a * D_ + m) * bf(W_qkv, m * D_ + c);
            WqT[c * D_ + a] = acc;
            if (c >= 64 && c < 128) W2b[a * 64 + (c - 64)] = __float2bfloat16(acc);
        } else {
            int t = idx - D_ * D_, a = t / D_, c = t % D_;
            float acc = 0.f;
            for (int m = 0; m < D_; m++)
                acc += bf(W_in, (D_ + a) * D_ + m) * bf(W_qkv, (D_ + m) * D_ + c);
            WkT[c * D_ + a] = acc;
            if (c >= 64 && c < 128) W2b[(192 + a) * 64 + (c - 64)] = __float2bfloat16(acc);
        }
    }
}

// ============ STAGE 2: compose_a2 (blocks 0..48) | nodeproj (49..816) ============
__global__ __launch_bounds__(256) void stage2_kernel(
    const bf16* W_in, const float* wo_eff, const float* bv_eff,
    const float* x2, const float* WqT, const float* WkT,
    const float* bq_eff, const float* bk_eff,
    float* t_m, float* sc, float* Tq1, float* Tq3, float* Tk1, float* Tk3) {
    int blk = blockIdx.x, tid = threadIdx.x;
    if (blk < 49) {  // ---- compose_a2: t_m, bvl ----
        int w = blk * 4 + (tid >> 6);
        int lane = tid & 63;
        float partial = 0.f;
        if (w < 192) {
            for (int aa = lane; aa < 192; aa += 64)
                partial += wo_eff[aa] * bf(W_in, (384 + aa) * 192 + w);
        } else if (w == 192) {
            for (int aa = lane; aa < 192; aa += 64) partial += wo_eff[aa] * bv_eff[aa];
        }
        for (int off = 32; off; off >>= 1) partial += __shfl_xor(partial, off, 64);
        if (lane == 0) {
            if (w < 192) t_m[w] = partial;
            else if (w == 192) sc[0] = partial;
        }
    } else {  // ---- nodeproj: coalesced via transposed tables ----
        int n = blk - 49;
        __shared__ float sx[64];
        if (tid < 64) sx[tid] = x2[n * 64 + tid];
        __syncthreads();
        if (tid < D_) {
            int a = tid;
            float q1 = bq_eff[a], q3 = 0.f, k1 = bk_eff[a], k3 = 0.f;
            for (int c = 0; c < 64; c++) {
                float xv = sx[c];
                q1 += WqT[c * D_ + a] * xv;
                q3 += WqT[(128 + c) * D_ + a] * xv;
                k1 += WkT[c * D_ + a] * xv;
                k3 += WkT[(128 + c) * D_ + a] * xv;
            }
            Tq1[n * D_ + a] = q1; Tq3[n * D_ + a] = q3;
            Tk1[n * D_ + a] = k1; Tk3[n * D_ + a] = k3;
        }
    }
}

// ============ K3: MFMA per-edge mid-GEMM + wvl + vl -> Q,K,vl ============
__global__ __launch_bounds__(256) void qkvmid_kernel(
    const bf16* edge_attr, const bf16* W_ee, const bf16* b_ee, const bf16* W2b,
    const bf16* W_qkv, const float* t_m, const float* sc, const float* x2,
    const float* Tq1, const float* Tq3, const float* Tk1, const float* Tk3,
    bf16* Q, bf16* K, float* vl) {
    __shared__ short s_w2[384 * 72];
    __shared__ short s_wk[32 * 72];
    __shared__ float s_tm[192], s_wvl[192];
    __shared__ int s_ni[32], s_nj[32];
    __shared__ float s_wraw[32], s_cls[32];
    int tid = threadIdx.x, base = blockIdx.x * 32;

    for (int c = tid; c < 3072; c += 256) {
        int row = c >> 3, off = c & 7;
        uint4 v = *(const uint4*)((const short*)W2b + row * 64 + off * 8);
        *(uint4*)&s_w2[row * 72 + off * 8] = v;
    }
    if (tid < 192) s_tm[tid] = t_m[tid];
    if (tid < 32) {
        int kk_g = base + tid;
        int b = kk_g / S_, kk = kk_g % S_;
        int q = kk >> 1, cls = kk & 1;
        int i = (int)((1.0f + sqrtf(8.0f * (float)q + 1.0f)) * 0.5f);
        while (i * (i - 1) / 2 > q) --i;
        while ((i + 1) * i / 2 <= q) ++i;
        int j = q - i * (i - 1) / 2;
        s_ni[tid] = b * N_ + i; s_nj[tid] = b * N_ + j;
        int e = (b * PAIRS + i * 47 + j) * 2 + cls;
        s_wraw[tid] = bf(edge_attr, e * 2);
        s_cls[tid] = (float)cls;
    }
    __syncthreads();
    for (int idx = tid; idx < 32 * 64; idx += 256) {
        int t = idx >> 6, h = idx & 63;
        int cls = (int)s_cls[t];
        float v = bf(W_ee, h * 3) * s_wraw[t] + bf(W_ee, h * 3 + 1 + cls) + bf(b_ee, h);
        bf16 bv = __float2bfloat16(fmaxf(v, 0.f));
        s_wk[t * 72 + h] = *reinterpret_cast<short*>(&bv);
    }
    if (tid < 192) {  // wvl[c] = t_m . W_qkv_v[:,c]  (redundant per block, cheap)
        float acc = 0.f;
        for (int m = 0; m < 192; m++) acc += s_tm[m] * bf(W_qkv, (384 + m) * 192 + tid);
        s_wvl[tid] = acc;
    }
    __syncthreads();

    int wave = tid >> 6, lane = tid & 63;
    int l5 = lane & 31, h5 = lane >> 5;

    short8 af[4];
    #pragma unroll
    for (int kc = 0; kc < 4; kc++)
        af[kc] = *(const short8*)&s_wk[l5 * 72 + kc * 16 + h5 * 8];

    int tl[16], niv[16], njv[16];
    #pragma unroll
    for (int r = 0; r < 16; r++) {
        int t = (r & 3) + 8 * (r >> 2) + 4 * h5;
        tl[r] = t; niv[r] = s_ni[t]; njv[r] = s_nj[t];
    }

    #pragma unroll
    for (int tt = 0; tt < 3; tt++) {
        int ta = wave + tt * 4;
        bool isq = ta < 6;
        int ag = (isq ? ta : ta - 6) * 32 + l5;
        float16v c;
        #pragma unroll
        for (int r = 0; r < 16; r++) c[r] = 0.f;
        #pragma unroll
        for (int kc = 0; kc < 4; kc++) {
            short8 bfr = *(const short8*)&s_w2[(ta * 32 + l5) * 72 + kc * 16 + h5 * 8];
            c = __builtin_amdgcn_mfma_f32_32x32x16_bf16(af[kc], bfr, c, 0, 0, 0);
        }
        const float* T1 = isq ? Tq1 : Tk1;
        const float* T3 = isq ? Tq3 : Tk3;
        bf16* Out = isq ? Q : K;
        #pragma unroll
        for (int r = 0; r < 16; r++) {
            float v = c[r] + T1[niv[r] * D_ + ag] + T3[njv[r] * D_ + ag];
            if (isq) v *= QSCALE;
            Out[(long)(base + tl[r]) * D_ + ag] = __float2bfloat16(v);
        }
    }
    if (tid < 32) {  // vl = sc0 + wvl . [x2_i | wK | x2_j]
        float v = sc[0];
        const float* xi = &x2[s_ni[tid] * 64];
        const float* xj = &x2[s_nj[tid] * 64];
        for (int h = 0; h < 64; h++) {
            v += s_wvl[h] * xi[h] + s_wvl[128 + h] * xj[h] +
                 s_wvl[64 + h] * u2f((unsigned short)s_wk[tid * 72 + h]);
        }
        vl[base + tid] = v;
    }
}

// ============ K4: split-K MFMA flash attention, 512 thr / 8 q-tiles ============
__device__ __forceinline__ void stage_k(const bf16* K, const float* vl, int b, int it,
                                        short* sk, float* svl, int tid) {
    {
        int c = tid;  // 768 chunks of 16B, 512 threads: pass 1
        int row = c / 24, cc = c % 24;
        int key = it * 32 + row;
        int gk = b * S_ + (key < S_ ? key : S_ - 1);
        *(uint4*)&sk[row * 200 + cc * 8] =
            *(const uint4*)((const short*)K + (long)gk * D_ + cc * 8);
    }
    if (tid < 256) {  // pass 2
        int c = tid + 512;
        int row = c / 24, cc = c % 24;
        int key = it * 32 + row;
        int gk = b * S_ + (key < S_ ? key : S_ - 1);
        *(uint4*)&sk[row * 200 + cc * 8] =
            *(const uint4*)((const short*)K + (long)gk * D_ + cc * 8);
    }
    if (tid < 32) {
        int key = it * 32 + tid;
        svl[tid] = (key < S_) ? vl[b * S_ + key] : 0.f;
    }
}

__global__ __launch_bounds__(512) void attn_kernel(const bf16* Q, const bf16* K,
                                                   const float* vl, float* part) {
    // 1152 blocks = 8 XCDs x (2 batches x 8 chunks x 9 q-groups)
    int x = blockIdx.x;
    int rr = x & 7, rest = x >> 3;       // rest 0..143
    int hi = rest >= 72;
    int b = rr + 8 * hi;
    int s = rest - 72 * hi;              // 0..71
    int chunk = s / 9, qg = s % 9;
    int tid = threadIdx.x;
    int wave = tid >> 6, lane = tid & 63;
    int n5 = lane & 31, h5 = lane >> 5;
    int qt = qg * 8 + wave;              // 0..71 (71 invalid)
    bool qvalid = qt < QTILES;
    int t0 = chunk * 9;
    int nit = (chunk == 7) ? 8 : 9;

    __shared__ short s_k[2][32 * 200];
    __shared__ float s_vl[2][32];

    short8 qf[12];
    {
        int qrow = b * S_ + qt * 32 + n5;
        if (qrow > B_ * S_ - 1) qrow = B_ * S_ - 1;
        const short* qp = (const short*)Q + (long)qrow * D_;
        #pragma unroll
        for (int kc = 0; kc < 12; kc++) qf[kc] = *(const short8*)(qp + kc * 16 + h5 * 8);
    }

    float lr[16], ar[16];
    #pragma unroll
    for (int r = 0; r < 16; r++) { lr[r] = 0.f; ar[r] = 0.f; }

    stage_k(K, vl, b, t0, s_k[0], s_vl[0], tid);

    for (int k = 0; k < nit; ++k) {
        int it = t0 + k;
        int buf = k & 1;
        __syncthreads();
        if (k + 1 < nit)
            stage_k(K, vl, b, it + 1, s_k[buf ^ 1], s_vl[buf ^ 1], tid);
        const short* kb = s_k[buf];
        float16v c;
        #pragma unroll
        for (int r = 0; r < 16; r++) c[r] = 0.f;
        #pragma unroll
        for (int kc = 0; kc < 12; kc++) {
            short8 bfr = *(const short8*)(kb + n5 * 200 + kc * 16 + h5 * 8);
            c = __builtin_amdgcn_mfma_f32_32x32x16_bf16(qf[kc], bfr, c, 0, 0, 0);
        }
        float vlv = s_vl[buf][n5];
        if (it != KITERS - 1) {
            #pragma unroll
            for (int r = 0; r < 16; r++) {
                float p = __builtin_amdgcn_exp2f(c[r]);
                lr[r] += p;
                ar[r] += p * vlv;
            }
        } else {
            bool kv = n5 < 16;
            #pragma unroll
            for (int r = 0; r < 16; r++) {
                float p = kv ? __builtin_amdgcn_exp2f(c[r]) : 0.f;
                lr[r] += p;
                ar[r] += p * vlv;
            }
        }
    }

    if (qvalid) {
        #pragma unroll
        for (int r = 0; r < 16; r++) {
            float l = lr[r], a = ar[r];
            #pragma unroll
            for (int off = 1; off < 32; off <<= 1) {
                l += __shfl_xor(l, off, 64);
                a += __shfl_xor(a, off, 64);
            }
            if (n5 == 0) {
                int qrow = qt * 32 + (r & 3) + 8 * (r >> 2) + 4 * h5;
                if (qrow < S_) {
                    float2v pv = {l, a};
                    *(float2v*)&part[((long)(b * S_ + qrow) * 8 + chunk) * 2] = pv;
                }
            }
        }
    }
}

// ============ K5: merge partials + pairing/argmin ============
__global__ __launch_bounds__(256) void final_kernel(const float* part, const float* sc,
                                                    float* out) {
    int idx = blockIdx.x * 256 + threadIdx.x;
    if (idx >= B_ * SH) return;
    int b = idx / SH, p = idx % SH;
    int i = (int)((1.0f + sqrtf(8.0f * (float)p + 1.0f)) * 0.5f);
    while (i * (i - 1) / 2 > p) --i;
    while ((i + 1) * i / 2 <= p) ++i;
    int j = p - i * (i - 1) / 2;
    float co = sc[1];
    float lg[2];
    #pragma unroll
    for (int t = 0; t < 2; t++) {
        long g = (long)b * S_ + 2 * p + t;
        float l = 0.f, a = 0.f;
        #pragma unroll
        for (int c = 0; c < 8; c++) {
            float2v pc = *(const float2v*)&part[(g * 8 + c) * 2];
            l += pc.x;
            a += pc.y;
        }
        lg[t] = sanitize(a / l + co);
    }
    int ind = (lg[1] < lg[0]) ? 1 : 0;
    float ef = ind ? lg[1] : lg[0];
    out[(b * SH + p) * 2 + 0] = (float)(b * N_ + i);
    out[(b * SH + p) * 2 + 1] = (float)(b * N_ + j);
    out[2 * B_ * SH + idx] = ef;
    out[2 * B_ * SH + B_ * SH + idx] = (float)ind;
}

extern "C" void kernel_launch(void* const* d_in, const int* in_sizes, int n_in,
                              void* d_out, int out_size, void* d_ws, size_t ws_size,
                              hipStream_t stream) {
    const bf16* x         = (const bf16*)d_in[0];
    const bf16* edge_attr = (const bf16*)d_in[2];
    const bf16* W_we   = (const bf16*)d_in[5];
    const bf16* b_we   = (const bf16*)d_in[6];
    const bf16* Wrel1  = (const bf16*)d_in[7];
    const bf16* brel1  = (const bf16*)d_in[8];
    const bf16* Wroot1 = (const bf16*)d_in[9];
    const bf16* Wrel2  = (const bf16*)d_in[10];
    const bf16* brel2  = (const bf16*)d_in[11];
    const bf16* Wroot2 = (const bf16*)d_in[12];
    const bf16* W_ee   = (const bf16*)d_in[13];
    const bf16* b_ee   = (const bf16*)d_in[14];
    const bf16* W_qkv  = (const bf16*)d_in[15];
    const bf16* b_qkv  = (const bf16*)d_in[16];
    const bf16* W_in   = (const bf16*)d_in[17];
    const bf16* b_in   = (const bf16*)d_in[18];
    const bf16* W_out  = (const bf16*)d_in[19];
    const bf16* b_out  = (const bf16*)d_in[20];
    const bf16* W_o    = (const bf16*)d_in[21];
    const bf16* b_o    = (const bf16*)d_in[22];

    float* w = (float*)d_ws;
    float* WqT    = w;                  // 36864
    float* WkT    = WqT + 36864;        // 36864
    float* t_m    = WkT + 36864;        // 192
    float* bq_eff = t_m + 192;
    float* bk_eff = bq_eff + 192;
    float* bv_eff = bk_eff + 192;
    float* wo_eff = bv_eff + 192;
    float* sc     = wo_eff + 192;       // 64 (2 used)
    float* x2     = sc + 64;            // 49152
    float* vl     = x2 + 49152;         // 36096
    float* part   = vl + 36096;         // 577536
    bf16*  Q      = (bf16*)(part + 577536);   // EK*192 bf16
    bf16*  K      = Q + (long)EK * D_;        // EK*192 bf16
    bf16*  W2b    = K + (long)EK * D_;        // 384*64 bf16
    float* Tq1    = (float*)(W2b + 384 * 64);
    float* Tq3    = Tq1 + NODES * D_;
    float* Tk1    = Tq3 + NODES * D_;
    float* Tk3    = Tk1 + NODES * D_;
    // total ~36 MB of 256 MB workspace

    stage1_kernel<<<497, 256, 0, stream>>>(edge_attr, W_we, b_we, x, Wrel1, brel1, Wroot1,
                                           Wrel2, brel2, Wroot2, W_o, b_o, W_out, b_out,
                                           W_in, b_in, b_qkv, W_qkv,
                                           x2, wo_eff, bq_eff, bk_eff, bv_eff, sc,
                                           WqT, WkT, W2b);
    stage2_kernel<<<817, 256, 0, stream>>>(W_in, wo_eff, bv_eff, x2, WqT, WkT,
                                           bq_eff, bk_eff, t_m, sc, Tq1, Tq3, Tk1, Tk3);
    qkvmid_kernel<<<EK / 32, 256, 0, stream>>>(edge_attr, W_ee, b_ee, W2b, W_qkv, t_m, sc, x2,
                                               Tq1, Tq3, Tk1, Tk3, Q, K, vl);
    attn_kernel<<<1152, 512, 0, stream>>>(Q, K, vl, part);
    final_kernel<<<(B_ * SH + 255) / 256, 256, 0, stream>>>(part, sc, (float*)d_out);
}

// Round 12
// 256.796 us; speedup vs baseline: 14.2186x; 1.0649x over previous
//
#include <hip/hip_runtime.h>
#include <hip/hip_bf16.h>

typedef __hip_bfloat16 bf16;
typedef __attribute__((ext_vector_type(8))) short short8;
typedef __attribute__((ext_vector_type(16))) float float16v;
typedef __attribute__((ext_vector_type(2))) float float2v;

#define B_     16
#define N_     48
#define NODES  768
#define PAIRS  2256
#define EK     36096
#define S_     2256
#define SH     1128
#define D_     192
#define KITERS 71
#define QTILES 71
#define QSCALE 0.10411754f  // log2(e)/sqrt(192): folded into Q at store

__device__ __forceinline__ float bf(const bf16* p, int i) { return __bfloat162float(p[i]); }
__device__ __forceinline__ float u2f(unsigned short u) {
    return __uint_as_float(((unsigned int)u) << 16);
}
__device__ __forceinline__ float sanitize(float v) {
    if (v > -1e4f && v < 1e4f) return v;
    if (v >= 1e4f) return 1e4f;
    if (v <= -1e4f) return -1e4f;
    return 0.f;  // NaN
}

// ============ STAGE 1: graphconv (blocks 0..15) | compose_a1 (16..208) |
// ============          compose_b (209..496)  — mutually independent ============
__global__ __launch_bounds__(256) void stage1_kernel(
    const bf16* edge_attr, const bf16* W_we, const bf16* b_we, const bf16* x,
    const bf16* Wrel1, const bf16* brel1, const bf16* Wroot1,
    const bf16* Wrel2, const bf16* brel2, const bf16* Wroot2,
    const bf16* W_o, const bf16* b_o, const bf16* W_out, const bf16* b_out,
    const bf16* W_in, const bf16* b_in, const bf16* b_qkv, const bf16* W_qkv,
    float* x2out, float* wo_eff, float* bq_eff, float* bk_eff, float* bv_eff, float* sc,
    float* WqT, float* WkT, bf16* W2b) {
    int blk = blockIdx.x, tid = threadIdx.x;
    if (blk < 16) {  // ---- graphconv, one block per batch ----
        int b = blk;
        __shared__ float s_ws[N_ * N_];
        __shared__ float s_x[N_ * 5], s_agg1[N_ * 5];
        __shared__ float s_x1[N_ * 32], s_agg2[N_ * 32];
        float we0 = bf(W_we, 0), we1 = bf(W_we, 1), we2 = bf(W_we, 2), bw = bf(b_we, 0);
        for (int idx = tid; idx < N_ * N_; idx += 256) {
            int i = idx / N_, j = idx % N_;
            float v = 0.f;
            if (i != j) {
                int p = i * 47 + (j < i ? j : j - 1);
                int e = (b * PAIRS + p) * 2;
                float w0 = fmaxf(we0 * bf(edge_attr, (e + 0) * 2) + we1 + bw, 0.f);
                float w1 = fmaxf(we0 * bf(edge_attr, (e + 1) * 2) + we2 + bw, 0.f);
                v = w0 + w1;
            }
            s_ws[idx] = v;
        }
        for (int idx = tid; idx < N_ * 5; idx += 256) s_x[idx] = bf(x, b * N_ * 5 + idx);
        __syncthreads();
        if (tid < 240) {
            int j = tid / 5, f = tid % 5;
            float a = 0.f;
            for (int i = 0; i < N_; i++) a += s_ws[i * N_ + j] * s_x[i * 5 + f];
            s_agg1[tid] = a;
        }
        __syncthreads();
        for (int o = tid; o < N_ * 32; o += 256) {
            int j = o >> 5, h = o & 31;
            float a = bf(brel1, h);
            for (int f = 0; f < 5; f++)
                a += bf(Wrel1, h * 5 + f) * s_agg1[j * 5 + f] +
                     bf(Wroot1, h * 5 + f) * s_x[j * 5 + f];
            s_x1[o] = fmaxf(a, 0.f);
        }
        __syncthreads();
        for (int o = tid; o < N_ * 32; o += 256) {
            int j = o >> 5, h = o & 31;
            float a = 0.f;
            for (int i = 0; i < N_; i++) a += s_ws[i * N_ + j] * s_x1[i * 32 + h];
            s_agg2[o] = a;
        }
        __syncthreads();
        for (int o = tid; o < N_ * 64; o += 256) {
            int j = o >> 6, h2 = o & 63;
            float a = bf(brel2, h2);
            for (int h1 = 0; h1 < 32; h1++)
                a += bf(Wrel2, h2 * 32 + h1) * s_agg2[j * 32 + h1] +
                     bf(Wroot2, h2 * 32 + h1) * s_x1[j * 32 + h1];
            x2out[(b * N_ + j) * 64 + h2] = fmaxf(a, 0.f);
        }
    } else if (blk < 209) {  // ---- compose_a1 ----
        int a = blk - 16;  // 0..191 outputs; 192 = co
        int wave = tid >> 6, lane = tid & 63;
        float partial = 0.f;
        if (a < 192) {
            if (wave == 0) {
                for (int m = lane; m < 192; m += 64)
                    partial += bf(W_o, m) * bf(W_out, m * 192 + a);
            } else {
                int row = (wave - 1) * 192 + a;
                for (int m = lane; m < 192; m += 64)
                    partial += bf(W_in, row * 192 + m) * bf(b_qkv, (wave - 1) * 192 + m);
            }
        } else if (wave == 0) {
            for (int m = lane; m < 192; m += 64) partial += bf(W_o, m) * bf(b_out, m);
        }
        for (int off = 32; off; off >>= 1) partial += __shfl_xor(partial, off, 64);
        if (lane == 0) {
            if (a < 192) {
                if (wave == 0) wo_eff[a] = partial;
                else if (wave == 1) bq_eff[a] = partial + bf(b_in, a);
                else if (wave == 2) bk_eff[a] = partial + bf(b_in, 192 + a);
                else bv_eff[a] = partial + bf(b_in, 384 + a);
            } else if (wave == 0) sc[1] = partial + bf(b_o, 0);
        }
    } else {  // ---- compose_b: Wq/Wk transposed tables + W2b bf16 ----
        int idx = (blk - 209) * 256 + tid;  // 0 .. 2*D*D-1
        if (idx < D_ * D_) {
            int a = idx / D_, c = idx % D_;
            float acc = 0.f;
            for (int m = 0; m < D_; m++) acc += bf(W_in, a * D_ + m) * bf(W_qkv, m * D_ + c);
            WqT[c * D_ + a] = acc;
            if (c >= 64 && c < 128) W2b[a * 64 + (c - 64)] = __float2bfloat16(acc);
        } else {
            int t = idx - D_ * D_, a = t / D_, c = t % D_;
            float acc = 0.f;
            for (int m = 0; m < D_; m++)
                acc += bf(W_in, (D_ + a) * D_ + m) * bf(W_qkv, (D_ + m) * D_ + c);
            WkT[c * D_ + a] = acc;
            if (c >= 64 && c < 128) W2b[(192 + a) * 64 + (c - 64)] = __float2bfloat16(acc);
        }
    }
}

// ============ STAGE 2: compose_a2 (blocks 0..48) | nodeproj (49..816) ============
__global__ __launch_bounds__(256) void stage2_kernel(
    const bf16* W_in, const float* wo_eff, const float* bv_eff,
    const float* x2, const float* WqT, const float* WkT,
    const float* bq_eff, const float* bk_eff,
    float* t_m, float* sc, float* Tq1, float* Tq3, float* Tk1, float* Tk3) {
    int blk = blockIdx.x, tid = threadIdx.x;
    if (blk < 49) {  // ---- compose_a2: t_m, bvl ----
        int w = blk * 4 + (tid >> 6);
        int lane = tid & 63;
        float partial = 0.f;
        if (w < 192) {
            for (int aa = lane; aa < 192; aa += 64)
                partial += wo_eff[aa] * bf(W_in, (384 + aa) * 192 + w);
        } else if (w == 192) {
            for (int aa = lane; aa < 192; aa += 64) partial += wo_eff[aa] * bv_eff[aa];
        }
        for (int off = 32; off; off >>= 1) partial += __shfl_xor(partial, off, 64);
        if (lane == 0) {
            if (w < 192) t_m[w] = partial;
            else if (w == 192) sc[0] = partial;
        }
    } else {  // ---- nodeproj: coalesced via transposed tables ----
        int n = blk - 49;
        __shared__ float sx[64];
        if (tid < 64) sx[tid] = x2[n * 64 + tid];
        __syncthreads();
        if (tid < D_) {
            int a = tid;
            float q1 = bq_eff[a], q3 = 0.f, k1 = bk_eff[a], k3 = 0.f;
            for (int c = 0; c < 64; c++) {
                float xv = sx[c];
                q1 += WqT[c * D_ + a] * xv;
                q3 += WqT[(128 + c) * D_ + a] * xv;
                k1 += WkT[c * D_ + a] * xv;
                k3 += WkT[(128 + c) * D_ + a] * xv;
            }
            Tq1[n * D_ + a] = q1; Tq3[n * D_ + a] = q3;
            Tk1[n * D_ + a] = k1; Tk3[n * D_ + a] = k3;
        }
    }
}

// ============ K3: MFMA per-edge mid-GEMM + wvl + vl -> Q,K,vl ============
__global__ __launch_bounds__(256) void qkvmid_kernel(
    const bf16* edge_attr, const bf16* W_ee, const bf16* b_ee, const bf16* W2b,
    const bf16* W_qkv, const float* t_m, const float* sc, const float* x2,
    const float* Tq1, const float* Tq3, const float* Tk1, const float* Tk3,
    bf16* Q, bf16* K, float* vl) {
    __shared__ short s_w2[384 * 72];
    __shared__ short s_wk[32 * 72];
    __shared__ float s_tm[192], s_wvl[192];
    __shared__ int s_ni[32], s_nj[32];
    __shared__ float s_wraw[32], s_cls[32];
    int tid = threadIdx.x, base = blockIdx.x * 32;

    for (int c = tid; c < 3072; c += 256) {
        int row = c >> 3, off = c & 7;
        uint4 v = *(const uint4*)((const short*)W2b + row * 64 + off * 8);
        *(uint4*)&s_w2[row * 72 + off * 8] = v;
    }
    if (tid < 192) s_tm[tid] = t_m[tid];
    if (tid < 32) {
        int kk_g = base + tid;
        int b = kk_g / S_, kk = kk_g % S_;
        int q = kk >> 1, cls = kk & 1;
        int i = (int)((1.0f + sqrtf(8.0f * (float)q + 1.0f)) * 0.5f);
        while (i * (i - 1) / 2 > q) --i;
        while ((i + 1) * i / 2 <= q) ++i;
        int j = q - i * (i - 1) / 2;
        s_ni[tid] = b * N_ + i; s_nj[tid] = b * N_ + j;
        int e = (b * PAIRS + i * 47 + j) * 2 + cls;
        s_wraw[tid] = bf(edge_attr, e * 2);
        s_cls[tid] = (float)cls;
    }
    __syncthreads();
    for (int idx = tid; idx < 32 * 64; idx += 256) {
        int t = idx >> 6, h = idx & 63;
        int cls = (int)s_cls[t];
        float v = bf(W_ee, h * 3) * s_wraw[t] + bf(W_ee, h * 3 + 1 + cls) + bf(b_ee, h);
        bf16 bv = __float2bfloat16(fmaxf(v, 0.f));
        s_wk[t * 72 + h] = *reinterpret_cast<short*>(&bv);
    }
    if (tid < 192) {  // wvl[c] = t_m . W_qkv_v[:,c]  (redundant per block, cheap)
        float acc = 0.f;
        for (int m = 0; m < 192; m++) acc += s_tm[m] * bf(W_qkv, (384 + m) * 192 + tid);
        s_wvl[tid] = acc;
    }
    __syncthreads();

    int wave = tid >> 6, lane = tid & 63;
    int l5 = lane & 31, h5 = lane >> 5;

    short8 af[4];
    #pragma unroll
    for (int kc = 0; kc < 4; kc++)
        af[kc] = *(const short8*)&s_wk[l5 * 72 + kc * 16 + h5 * 8];

    int tl[16], niv[16], njv[16];
    #pragma unroll
    for (int r = 0; r < 16; r++) {
        int t = (r & 3) + 8 * (r >> 2) + 4 * h5;
        tl[r] = t; niv[r] = s_ni[t]; njv[r] = s_nj[t];
    }

    #pragma unroll
    for (int tt = 0; tt < 3; tt++) {
        int ta = wave + tt * 4;
        bool isq = ta < 6;
        int ag = (isq ? ta : ta - 6) * 32 + l5;
        float16v c;
        #pragma unroll
        for (int r = 0; r < 16; r++) c[r] = 0.f;
        #pragma unroll
        for (int kc = 0; kc < 4; kc++) {
            short8 bfr = *(const short8*)&s_w2[(ta * 32 + l5) * 72 + kc * 16 + h5 * 8];
            c = __builtin_amdgcn_mfma_f32_32x32x16_bf16(af[kc], bfr, c, 0, 0, 0);
        }
        const float* T1 = isq ? Tq1 : Tk1;
        const float* T3 = isq ? Tq3 : Tk3;
        bf16* Out = isq ? Q : K;
        #pragma unroll
        for (int r = 0; r < 16; r++) {
            float v = c[r] + T1[niv[r] * D_ + ag] + T3[njv[r] * D_ + ag];
            if (isq) v *= QSCALE;
            Out[(long)(base + tl[r]) * D_ + ag] = __float2bfloat16(v);
        }
    }
    if (tid < 32) {  // vl = sc0 + wvl . [x2_i | wK | x2_j]
        float v = sc[0];
        const float* xi = &x2[s_ni[tid] * 64];
        const float* xj = &x2[s_nj[tid] * 64];
        for (int h = 0; h < 64; h++) {
            v += s_wvl[h] * xi[h] + s_wvl[128 + h] * xj[h] +
                 s_wvl[64 + h] * u2f((unsigned short)s_wk[tid * 72 + h]);
        }
        vl[base + tid] = v;
    }
}

// ============ K4: attn — register-prefetch pipelined staging ============
__global__ __launch_bounds__(512) void attn_kernel(const bf16* Q, const bf16* K,
                                                   const float* vl, float* part) {
    // 1152 blocks = 8 XCDs x (2 batches x 8 chunks x 9 q-groups)
    int x = blockIdx.x;
    int rr = x & 7, rest = x >> 3;       // rest 0..143
    int hi = rest >= 72;
    int b = rr + 8 * hi;
    int s = rest - 72 * hi;              // 0..71
    int chunk = s / 9, qg = s % 9;
    int tid = threadIdx.x;
    int wave = tid >> 6, lane = tid & 63;
    int n5 = lane & 31, h5 = lane >> 5;
    int qt = qg * 8 + wave;              // 0..71 (71 invalid)
    bool qvalid = qt < QTILES;
    int t0 = chunk * 9;
    int nit = (chunk == 7) ? 8 : 9;

    __shared__ short s_k[2][32 * 200];
    __shared__ float s_vl[2][32];

    // fixed per-thread staging coordinates (768 x 16B chunks, 1.5 per thread)
    int row0 = tid / 24, cc0 = tid % 24;
    int c1 = tid + 512;
    int row1 = c1 / 24, cc1 = c1 % 24;
    bool has1 = tid < 256;

    short8 qf[12];
    {
        int qrow = b * S_ + qt * 32 + n5;
        if (qrow > B_ * S_ - 1) qrow = B_ * S_ - 1;
        const short* qp = (const short*)Q + (long)qrow * D_;
        #pragma unroll
        for (int kc = 0; kc < 12; kc++) qf[kc] = *(const short8*)(qp + kc * 16 + h5 * 8);
    }

    float lr[16], ar[16];
    #pragma unroll
    for (int r = 0; r < 16; r++) { lr[r] = 0.f; ar[r] = 0.f; }

    // prefetch tile t0 into registers
    uint4 p0, p1; float pv = 0.f;
    {
        int key = t0 * 32 + row0;
        int gk = b * S_ + (key < S_ ? key : S_ - 1);
        p0 = *(const uint4*)((const short*)K + (long)gk * D_ + cc0 * 8);
        if (has1) {
            int key1 = t0 * 32 + row1;
            int gk1 = b * S_ + (key1 < S_ ? key1 : S_ - 1);
            p1 = *(const uint4*)((const short*)K + (long)gk1 * D_ + cc1 * 8);
        }
        if (tid < 32) {
            int key2 = t0 * 32 + tid;
            pv = (key2 < S_) ? vl[b * S_ + key2] : 0.f;
        }
    }

    for (int k = 0; k < nit; ++k) {
        int it = t0 + k;
        int buf = k & 1;
        // store prefetched tile k into LDS[buf] (vmcnt drain was hidden by prior compute)
        *(uint4*)&s_k[buf][row0 * 200 + cc0 * 8] = p0;
        if (has1) *(uint4*)&s_k[buf][row1 * 200 + cc1 * 8] = p1;
        if (tid < 32) s_vl[buf][tid] = pv;
        // issue loads for tile k+1 (fly during this iteration's compute)
        if (k + 1 < nit) {
            int it1 = it + 1;
            int key = it1 * 32 + row0;
            int gk = b * S_ + (key < S_ ? key : S_ - 1);
            p0 = *(const uint4*)((const short*)K + (long)gk * D_ + cc0 * 8);
            if (has1) {
                int key1 = it1 * 32 + row1;
                int gk1 = b * S_ + (key1 < S_ ? key1 : S_ - 1);
                p1 = *(const uint4*)((const short*)K + (long)gk1 * D_ + cc1 * 8);
            }
            if (tid < 32) {
                int key2 = it1 * 32 + tid;
                pv = (key2 < S_) ? vl[b * S_ + key2] : 0.f;
            }
        }
        __syncthreads();   // LDS[buf] fully staged; LDS[buf^1] readers are 2 iters back
        const short* kb = s_k[buf];
        float16v c;
        #pragma unroll
        for (int r = 0; r < 16; r++) c[r] = 0.f;
        #pragma unroll
        for (int kc = 0; kc < 12; kc++) {
            short8 bfr = *(const short8*)(kb + n5 * 200 + kc * 16 + h5 * 8);
            c = __builtin_amdgcn_mfma_f32_32x32x16_bf16(qf[kc], bfr, c, 0, 0, 0);
        }
        float vlv = s_vl[buf][n5];
        if (it != KITERS - 1) {
            #pragma unroll
            for (int r = 0; r < 16; r++) {
                float p = __builtin_amdgcn_exp2f(c[r]);
                lr[r] += p;
                ar[r] += p * vlv;
            }
        } else {
            bool kv = n5 < 16;
            #pragma unroll
            for (int r = 0; r < 16; r++) {
                float p = kv ? __builtin_amdgcn_exp2f(c[r]) : 0.f;
                lr[r] += p;
                ar[r] += p * vlv;
            }
        }
    }

    if (qvalid) {
        #pragma unroll
        for (int r = 0; r < 16; r++) {
            float l = lr[r], a = ar[r];
            #pragma unroll
            for (int off = 1; off < 32; off <<= 1) {
                l += __shfl_xor(l, off, 64);
                a += __shfl_xor(a, off, 64);
            }
            if (n5 == 0) {
                int qrow = qt * 32 + (r & 3) + 8 * (r >> 2) + 4 * h5;
                if (qrow < S_) {
                    float2v pv2 = {l, a};
                    *(float2v*)&part[((long)(b * S_ + qrow) * 8 + chunk) * 2] = pv2;
                }
            }
        }
    }
}

// ============ K5: merge partials + pairing/argmin ============
__global__ __launch_bounds__(256) void final_kernel(const float* part, const float* sc,
                                                    float* out) {
    int idx = blockIdx.x * 256 + threadIdx.x;
    if (idx >= B_ * SH) return;
    int b = idx / SH, p = idx % SH;
    int i = (int)((1.0f + sqrtf(8.0f * (float)p + 1.0f)) * 0.5f);
    while (i * (i - 1) / 2 > p) --i;
    while ((i + 1) * i / 2 <= p) ++i;
    int j = p - i * (i - 1) / 2;
    float co = sc[1];
    float lg[2];
    #pragma unroll
    for (int t = 0; t < 2; t++) {
        long g = (long)b * S_ + 2 * p + t;
        float l = 0.f, a = 0.f;
        #pragma unroll
        for (int c = 0; c < 8; c++) {
            float2v pc = *(const float2v*)&part[(g * 8 + c) * 2];
            l += pc.x;
            a += pc.y;
        }
        lg[t] = sanitize(a / l + co);
    }
    int ind = (lg[1] < lg[0]) ? 1 : 0;
    float ef = ind ? lg[1] : lg[0];
    out[(b * SH + p) * 2 + 0] = (float)(b * N_ + i);
    out[(b * SH + p) * 2 + 1] = (float)(b * N_ + j);
    out[2 * B_ * SH + idx] = ef;
    out[2 * B_ * SH + B_ * SH + idx] = (float)ind;
}

extern "C" void kernel_launch(void* const* d_in, const int* in_sizes, int n_in,
                              void* d_out, int out_size, void* d_ws, size_t ws_size,
                              hipStream_t stream) {
    const bf16* x         = (const bf16*)d_in[0];
    const bf16* edge_attr = (const bf16*)d_in[2];
    const bf16* W_we   = (const bf16*)d_in[5];
    const bf16* b_we   = (const bf16*)d_in[6];
    const bf16* Wrel1  = (const bf16*)d_in[7];
    const bf16* brel1  = (const bf16*)d_in[8];
    const bf16* Wroot1 = (const bf16*)d_in[9];
    const bf16* Wrel2  = (const bf16*)d_in[10];
    const bf16* brel2  = (const bf16*)d_in[11];
    const bf16* Wroot2 = (const bf16*)d_in[12];
    const bf16* W_ee   = (const bf16*)d_in[13];
    const bf16* b_ee   = (const bf16*)d_in[14];
    const bf16* W_qkv  = (const bf16*)d_in[15];
    const bf16* b_qkv  = (const bf16*)d_in[16];
    const bf16* W_in   = (const bf16*)d_in[17];
    const bf16* b_in   = (const bf16*)d_in[18];
    const bf16* W_out  = (const bf16*)d_in[19];
    const bf16* b_out  = (const bf16*)d_in[20];
    const bf16* W_o    = (const bf16*)d_in[21];
    const bf16* b_o    = (const bf16*)d_in[22];

    float* w = (float*)d_ws;
    float* WqT    = w;                  // 36864
    float* WkT    = WqT + 36864;        // 36864
    float* t_m    = WkT + 36864;        // 192
    float* bq_eff = t_m + 192;
    float* bk_eff = bq_eff + 192;
    float* bv_eff = bk_eff + 192;
    float* wo_eff = bv_eff + 192;
    float* sc     = wo_eff + 192;       // 64 (2 used)
    float* x2     = sc + 64;            // 49152
    float* vl     = x2 + 49152;         // 36096
    float* part   = vl + 36096;         // 577536
    bf16*  Q      = (bf16*)(part + 577536);   // EK*192 bf16
    bf16*  K      = Q + (long)EK * D_;        // EK*192 bf16
    bf16*  W2b    = K + (long)EK * D_;        // 384*64 bf16
    float* Tq1    = (float*)(W2b + 384 * 64);
    float* Tq3    = Tq1 + NODES * D_;
    float* Tk1    = Tq3 + NODES * D_;
    float* Tk3    = Tk1 + NODES * D_;
    // total ~36 MB of 256 MB workspace

    stage1_kernel<<<497, 256, 0, stream>>>(edge_attr, W_we, b_we, x, Wrel1, brel1, Wroot1,
                                           Wrel2, brel2, Wroot2, W_o, b_o, W_out, b_out,
                                           W_in, b_in, b_qkv, W_qkv,
                                           x2, wo_eff, bq_eff, bk_eff, bv_eff, sc,
                                           WqT, WkT, W2b);
    stage2_kernel<<<817, 256, 0, stream>>>(W_in, wo_eff, bv_eff, x2, WqT, WkT,
                                           bq_eff, bk_eff, t_m, sc, Tq1, Tq3, Tk1, Tk3);
    qkvmid_kernel<<<EK / 32, 256, 0, stream>>>(edge_attr, W_ee, b_ee, W2b, W_qkv, t_m, sc, x2,
                                               Tq1, Tq3, Tk1, Tk3, Q, K, vl);
    attn_kernel<<<1152, 512, 0, stream>>>(Q, K, vl, part);
    final_kernel<<<(B_ * SH + 255) / 256, 256, 0, stream>>>(part, sc, (float*)d_out);
}